// Round 15
// baseline (98.275 us; speedup 1.0000x reference)
//
#include <hip/hip_runtime.h>

// B=2,G=1024,S=64,L=16,F=8 -> LF=128, ATT=128, RANK=32, HC=32, NH=4. NWIN=2048.
#define NWIN 2048

// ws layout (BYTE offsets). Total 87040 B (under proven 123392 budget).
#define QKVT8_OFF 0      // uchar [160][128]: rows 0-127 QT_tab^T x256; rows 128-159 Wkv_u^T x16
#define OT8_OFF  20480   // uchar [128][128]  O^T x128
#define W1T_OFF  36864   // short [128][128]  W1^T bf16 (x1)
#define W2T8_OFF 69632   // uchar [128][128]  W2^T x16
#define CVEC_OFF 86016   // float [128]
#define CSW1_OFF 86528   // float [128]  colsum of W1 (for LN2 fold)

typedef __attribute__((ext_vector_type(8))) __bf16 bf16x8;
typedef __attribute__((ext_vector_type(8))) short s16x8;
typedef __attribute__((ext_vector_type(4))) short s16x4;
typedef __attribute__((ext_vector_type(4))) float f32x4;

static __device__ inline short f2bf(float f) {
    __bf16 b = (__bf16)f;
    return __builtin_bit_cast(short, b);
}
static __device__ inline float bf2f(short h) {
    unsigned u = ((unsigned)(unsigned short)h) << 16;
    return __builtin_bit_cast(float, u);
}
static __device__ inline bf16x8 ldbf8(const short* p) {
    return __builtin_bit_cast(bf16x8, *(const s16x8*)p);
}
static __device__ inline unsigned char f2fp8(float v) {
    return (unsigned char)__builtin_amdgcn_cvt_pk_fp8_f32(v, v, 0u, false);
}
static __device__ inline long ld8(const void* p) {
    return *(const long*)p;
}

// ---------------- precompute: fp8 tables (scales exact powers of 2) ----------------
__global__ __launch_bounds__(256) void fam_pre(
    const float* __restrict__ Wq_u, const float* __restrict__ Wq_v,
    const float* __restrict__ Wkv_u, const float* __restrict__ Wkv_v,
    const float* __restrict__ kv_b, const float* __restrict__ Wo_u,
    const float* __restrict__ Wo_v, const float* __restrict__ W1,
    const float* __restrict__ W2, unsigned char* __restrict__ ws8)
{
    const int b = blockIdx.x, tid = threadIdx.x;
    float* cvec = (float*)(ws8 + CVEC_OFF);
    float* csW1 = (float*)(ws8 + CSW1_OFF);
    if (b < 16) {
        __shared__ float Wv[4096];   // Wkv_v v-part [r][c]
        __shared__ float Wu[4096];   // Wo_u [att][u]
        __shared__ float N[4096];    // N[h][u][r]
        for (int i = tid; i < 4096; i += 256) {
            int r = i >> 7, c = i & 127;
            Wv[i] = Wkv_v[r*256 + 128 + c];
            Wu[i] = Wo_u[i];
        }
        __syncthreads();
        for (int i = tid; i < 4096; i += 256) {
            int h = i >> 10, u = (i >> 5) & 31, r = i & 31;
            float acc = 0.f;
            for (int c = 0; c < 32; ++c) acc += Wv[r*128 + h*32 + c] * Wu[(h*32 + c)*32 + u];
            N[i] = acc;
        }
        __syncthreads();
        for (int i = tid; i < 1024; i += 256) {
            int jj = i >> 7, hr = i & 127;
            int j = b*8 + jj, h = hr >> 5, r = hr & 31;
            float acc = 0.f;
            for (int u = 0; u < 32; ++u) acc += N[h*1024 + u*32 + r] * Wo_v[u*128 + j];
            ws8[OT8_OFF + j*128 + hr] = f2fp8(acc * 128.f);
        }
    } else if (b < 32) {
        short* w1t = (short*)(ws8 + W1T_OFF);
        int i0 = (b - 16) * 8;
        for (int t = tid; t < 1024; t += 256) {
            int ii = t >> 7, k = t & 127, i = i0 + ii;
            w1t[i*128 + k] = f2bf(W1[k*128 + i]);
        }
        if (b == 16 && tid < 128) {
            float a = 0.f;
            for (int k = 0; k < 128; ++k) a += W1[k*128 + tid];
            csW1[tid] = a;
        }
    } else if (b < 48) {
        int j0 = (b - 32) * 8;
        for (int t = tid; t < 1024; t += 256) {
            int jj = t >> 7, k = t & 127, j = j0 + jj;
            ws8[W2T8_OFF + j*128 + k] = f2fp8(W2[k*128 + j] * 16.f);
        }
    } else {
        // QKVT slices: sl = 0..7; each builds M redundantly, writes 16 QT rows + 4 KV rows
        const int sl = b - 48;
        __shared__ float Msh[4096];   // M[h][u][r] (incl 1/sqrt32)
        __shared__ float ov[32];
        const float sc = 0.17677669529663687f;  // 1/sqrt(32)
        for (int i = tid; i < 4096; i += 256) {
            int h = i >> 10, u = (i >> 5) & 31, r = i & 31;
            float acc = 0.f;
            for (int c = 0; c < 32; ++c)
                acc += Wq_v[u*128 + h*32 + c] * Wkv_v[r*256 + h*32 + c];
            Msh[i] = acc * sc;
        }
        __syncthreads();
        for (int i = tid; i < 2048; i += 256) {
            int c = sl*16 + (i >> 7), k = i & 127;
            int h = c >> 5, r = c & 31;
            float acc = 0.f;
            for (int u = 0; u < 32; ++u) acc += Wq_u[k*32 + u] * Msh[h*1024 + u*32 + r];
            ws8[QKVT8_OFF + c*128 + k] = f2fp8(acc * 256.f);
        }
        for (int i = tid; i < 512; i += 256) {
            int u = sl*4 + (i >> 7), k = i & 127;
            ws8[QKVT8_OFF + (128 + u)*128 + k] = f2fp8(Wkv_u[k*32 + u] * 16.f);
        }
        if (sl == 0) {
            if (tid < 32) {
                float a = 0.f;
                for (int att = 0; att < 128; ++att) a += kv_b[128 + att] * Wo_u[att*32 + tid];
                ov[tid] = a;
            }
            __syncthreads();
            if (tid < 128) {
                float a = 0.f;
                for (int u = 0; u < 32; ++u) a += ov[u] * Wo_v[u*128 + tid];
                cvec[tid] = a;
            }
        }
    }
}

// ---------------- main fused kernel: 1 block = 1 window, 4 waves ----------------
// R14 + x1-liveness elimination: x1 lives only in XB (bf16); P9 re-reads it.
// LN2 folded into P8 (t = rinv*acc - rinv*mean*csW1 + b1) -> no XB rewrite.
// Frees the 32-reg x1v range -> (256,5) fits without spills; LDS 32000x5 <= 160K.
#define SRA 136   // RA8/XB byte/short stride
#define SHQ 40    // KV8 byte stride
#define SHB 72    // HB8/KVT8 byte stride

#define SM_RA8   0        //  8704  h -> pu -> t1 (fp8 [64][SRA])
#define SM_KV8   8704     //  2560  hu_kv x4 fp8 [64][SHQ] (A of scores)
#define SM_KVT8  11264    //  2304  hu_kv^T x4 fp8 [32][SHB] (B of PV)
#define SM_HB8   13568    // 18432  per head [64][SHB]: qt8/P8; later XB bf16 [64][136] (17408) + stats (512)
#define SM_STATS (SM_HB8 + 17408)
#define SM_TOTAL 32000

__global__ __launch_bounds__(256, 5) void fam_main(
    const float* __restrict__ x, const unsigned char* __restrict__ ws8,
    const float* __restrict__ gamma, const float* __restrict__ b1,
    const float* __restrict__ b2, const float* __restrict__ gmlp_p,
    float* __restrict__ out)
{
    __shared__ __align__(16) unsigned char SM[SM_TOTAL];
    unsigned char* RA8  = SM + SM_RA8;
    unsigned char* KV8  = SM + SM_KV8;
    unsigned char* KVT8 = SM + SM_KVT8;

    const float* cvec = (const float*)(ws8 + CVEC_OFF);
    const float* csW1 = (const float*)(ws8 + CSW1_OFF);
    const int tid = threadIdx.x;
    const int l   = tid & 63;
    const int wv  = tid >> 6;
    const int l15 = l & 15;
    const int lg  = l >> 4;
    const size_t base = (size_t)blockIdx.x * 8192;
    const float* __restrict__ xw   = x + base;
    float* __restrict__       outw = out + base;
    const int n0 = wv * 32;

    // ---- P1: LN1 -> h (fp8 x1) in RA8 ----
    {
        int s = tid >> 2, c = tid & 3;
        float4 xr1[8];
        float sum = 0.f, sq = 0.f;
        #pragma unroll
        for (int j = 0; j < 8; ++j) {
            xr1[j] = *(const float4*)&xw[s*128 + c*32 + j*4];
            sum += xr1[j].x + xr1[j].y + xr1[j].z + xr1[j].w;
            sq  += xr1[j].x*xr1[j].x + xr1[j].y*xr1[j].y + xr1[j].z*xr1[j].z + xr1[j].w*xr1[j].w;
        }
        sum += __shfl_xor(sum, 1); sq += __shfl_xor(sq, 1);
        sum += __shfl_xor(sum, 2); sq += __shfl_xor(sq, 2);
        float mean = sum * (1.f/128.f);
        float var  = sq * (1.f/128.f) - mean*mean;
        float rinv = rsqrtf(var + 1e-5f);
        #pragma unroll
        for (int j = 0; j < 8; ++j) {
            unsigned w = 0;
            w = __builtin_amdgcn_cvt_pk_fp8_f32((xr1[j].x - mean)*rinv, (xr1[j].y - mean)*rinv, w, false);
            w = __builtin_amdgcn_cvt_pk_fp8_f32((xr1[j].z - mean)*rinv, (xr1[j].w - mean)*rinv, w, true);
            *(unsigned*)&RA8[s*SRA + c*32 + j*4] = w;
        }
    }
    __syncthreads();   // B1

    // ---- P2 (fused): [QT(128) | KV(32)] = h @ QKVT8 ----
    {
        long bA[4], bB[4], bC[4];
        #pragma unroll
        for (int kb = 0; kb < 4; ++kb) {
            bA[kb] = ld8(ws8 + QKVT8_OFF + (wv*16 + l15)*128 + kb*32 + lg*8);
            bB[kb] = ld8(ws8 + QKVT8_OFF + ((wv + 4)*16 + l15)*128 + kb*32 + lg*8);
        }
        if (wv >= 2) {
            #pragma unroll
            for (int kb = 0; kb < 4; ++kb)
                bC[kb] = ld8(ws8 + QKVT8_OFF + ((6 + wv)*16 + l15)*128 + kb*32 + lg*8);
        }
        unsigned char* HBA = SM + SM_HB8 + (wv >> 1)*4608;
        unsigned char* HBB = SM + SM_HB8 + (2 + (wv >> 1))*4608;
        const int rr = (wv & 1)*16 + l15;
        #pragma unroll
        for (int m = 0; m < 4; ++m) {
            long a[4];
            #pragma unroll
            for (int kb = 0; kb < 4; ++kb)
                a[kb] = ld8(RA8 + (m*16 + l15)*SRA + kb*32 + lg*8);
            f32x4 accA = {0.f,0.f,0.f,0.f}, accB = {0.f,0.f,0.f,0.f};
            #pragma unroll
            for (int kb = 0; kb < 4; ++kb) {
                accA = __builtin_amdgcn_mfma_f32_16x16x32_fp8_fp8(a[kb], bA[kb], accA, 0, 0, 0);
                accB = __builtin_amdgcn_mfma_f32_16x16x32_fp8_fp8(a[kb], bB[kb], accB, 0, 0, 0);
            }
            #pragma unroll
            for (int j = 0; j < 4; ++j) {
                int row = (m*16 + lg*4 + j)*SHB;
                HBA[row + rr] = f2fp8(accA[j] * 0.25f);
                HBB[row + rr] = f2fp8(accB[j] * 0.25f);
            }
            if (wv >= 2) {
                f32x4 accC = {0.f,0.f,0.f,0.f};
                #pragma unroll
                for (int kb = 0; kb < 4; ++kb)
                    accC = __builtin_amdgcn_mfma_f32_16x16x32_fp8_fp8(a[kb], bC[kb], accC, 0, 0, 0);
                int u = (wv - 2)*16 + l15;
                #pragma unroll
                for (int j = 0; j < 4; ++j)
                    KV8[(m*16 + lg*4 + j)*SHQ + u] = f2fp8(accC[j] * 0.25f);
                unsigned w = 0;
                w = __builtin_amdgcn_cvt_pk_fp8_f32(accC[0]*0.25f, accC[1]*0.25f, w, false);
                w = __builtin_amdgcn_cvt_pk_fp8_f32(accC[2]*0.25f, accC[3]*0.25f, w, true);
                *(unsigned*)&KVT8[u*SHB + m*16 + lg*4] = w;
            }
        }
    }
    __syncthreads();   // B2

    // ---- P4/P5: per-head attention (h = wv) ----
    {
        const int h = wv;
        unsigned char* HB8h = SM + SM_HB8 + h*4608;
        long av[4], bq[4];
        #pragma unroll
        for (int m = 0; m < 4; ++m) av[m] = ld8(KV8 + (m*16 + l15)*SHQ + lg*8);
        #pragma unroll
        for (int n = 0; n < 4; ++n) bq[n] = ld8(HB8h + (n*16 + l15)*SHB + lg*8);
        f32x4 cc[4][4];
        #pragma unroll
        for (int m = 0; m < 4; ++m)
            #pragma unroll
            for (int n = 0; n < 4; ++n) {
                f32x4 z = {0.f, 0.f, 0.f, 0.f};
                cc[m][n] = __builtin_amdgcn_mfma_f32_16x16x32_fp8_fp8(av[m], bq[n], z, 0, 0, 0);
            }
        #pragma unroll
        for (int n = 0; n < 4; ++n) {
            float e[4][4];
            float sm = 0.f;
            #pragma unroll
            for (int m = 0; m < 4; ++m)
                #pragma unroll
                for (int j = 0; j < 4; ++j) {
                    e[m][j] = __expf(fminf(cc[m][n][j] * 0.00390625f, 30.f));
                    sm += e[m][j];
                }
            sm += __shfl_xor(sm, 16);
            sm += __shfl_xor(sm, 32);
            float rs64 = __builtin_amdgcn_rcpf(sm) * 64.f;
            int srow = (n*16 + l15) * SHB;
            #pragma unroll
            for (int m = 0; m < 4; ++m) {
                unsigned w = 0;
                w = __builtin_amdgcn_cvt_pk_fp8_f32(e[m][0]*rs64, e[m][1]*rs64, w, false);
                w = __builtin_amdgcn_cvt_pk_fp8_f32(e[m][2]*rs64, e[m][3]*rs64, w, true);
                *(unsigned*)&HB8h[srow + m*16 + lg*4] = w;
            }
        }
        long a8[4][2], b8[2][2];
        #pragma unroll
        for (int m = 0; m < 4; ++m)
            #pragma unroll
            for (int kb = 0; kb < 2; ++kb)
                a8[m][kb] = ld8(HB8h + (m*16 + l15)*SHB + kb*32 + lg*8);
        #pragma unroll
        for (int nn = 0; nn < 2; ++nn)
            #pragma unroll
            for (int kb = 0; kb < 2; ++kb)
                b8[nn][kb] = ld8(KVT8 + (nn*16 + l15)*SHB + kb*32 + lg*8);
        #pragma unroll
        for (int m = 0; m < 4; ++m)
            #pragma unroll
            for (int nn = 0; nn < 2; ++nn) {
                f32x4 acc = {0.f,0.f,0.f,0.f};
                acc = __builtin_amdgcn_mfma_f32_16x16x32_fp8_fp8(a8[m][0], b8[nn][0], acc, 0, 0, 0);
                acc = __builtin_amdgcn_mfma_f32_16x16x32_fp8_fp8(a8[m][1], b8[nn][1], acc, 0, 0, 0);
                #pragma unroll
                for (int j = 0; j < 4; ++j)
                    RA8[(m*16 + lg*4 + j)*SRA + h*32 + nn*16 + l15] = f2fp8(acc[j] * 0.03125f);
            }
    }
    __syncthreads();   // B3: pu8 in RA8; HB8 dead -> XB

    short* XB = (short*)(SM + SM_HB8);        // x1 bf16 [64][136] (stays raw through P9)
    float* stats = (float*)(SM + SM_STATS);   // [64][2] mean,rinv

    // ---- P6: upd = pu8 @ O8; x1 = x + gm*(acc/1024 + cv) -> XB only ----
    {
        long bo[2][4];
        float cv[2], gm[2];
        #pragma unroll
        for (int nn = 0; nn < 2; ++nn) {
            int col = n0 + nn*16 + l15;
            #pragma unroll
            for (int kb = 0; kb < 4; ++kb)
                bo[nn][kb] = ld8(ws8 + OT8_OFF + col*128 + kb*32 + lg*8);
            cv[nn] = cvec[col];
            gm[nn] = gamma[col];
        }
        #pragma unroll
        for (int m = 0; m < 4; ++m) {
            long a[4];
            #pragma unroll
            for (int kb = 0; kb < 4; ++kb)
                a[kb] = ld8(RA8 + (m*16 + l15)*SRA + kb*32 + lg*8);
            #pragma unroll
            for (int nn = 0; nn < 2; ++nn) {
                f32x4 acc = {0.f,0.f,0.f,0.f};
                #pragma unroll
                for (int kb = 0; kb < 4; ++kb)
                    acc = __builtin_amdgcn_mfma_f32_16x16x32_fp8_fp8(a[kb], bo[nn][kb], acc, 0, 0, 0);
                int col = n0 + nn*16 + l15;
                #pragma unroll
                for (int j = 0; j < 4; ++j) {
                    int row = m*16 + lg*4 + j;
                    float xv = xw[row*128 + col];
                    float v = xv + gm[nn] * (acc[j] * 9.765625e-4f + cv[nn]);
                    XB[row*SRA + col] = f2bf(v);
                }
            }
        }
    }
    __syncthreads();   // B4: x1 bf16 in XB complete

    // ---- P7: LN2 stats only (no XB rewrite) ----
    {
        int s = tid >> 2, c = tid & 3;
        float sum = 0.f, sq = 0.f;
        #pragma unroll
        for (int jj = 0; jj < 8; ++jj) {
            s16x4 hv = *(const s16x4*)&XB[s*SRA + c*32 + jj*4];
            #pragma unroll
            for (int e = 0; e < 4; ++e) {
                float f = bf2f(hv[e]);
                sum += f; sq += f*f;
            }
        }
        sum += __shfl_xor(sum, 1); sq += __shfl_xor(sq, 1);
        sum += __shfl_xor(sum, 2); sq += __shfl_xor(sq, 2);
        if (c == 0) {
            float mean = sum * (1.f/128.f);
            float var  = sq * (1.f/128.f) - mean*mean;
            stats[s*2]     = mean;
            stats[s*2 + 1] = rsqrtf(var + 1e-5f);
        }
    }
    __syncthreads();   // B5: stats ready; XB still holds raw x1

    // ---- P8: t1 = gelu(LNfold(x1 @ W1)) -> t1 x8 fp8 into RA8 ----
    {
        const short* W1t = (const short*)(ws8 + W1T_OFF);
        bf16x8 bw1[2][4];
        float bb1[2], cw1[2];
        #pragma unroll
        for (int nn = 0; nn < 2; ++nn) {
            int col = n0 + nn*16 + l15;
            #pragma unroll
            for (int k = 0; k < 4; ++k)
                bw1[nn][k] = ldbf8(&W1t[col*128 + k*32 + lg*8]);
            bb1[nn] = b1[col];
            cw1[nn] = csW1[col];
        }
        #pragma unroll
        for (int m = 0; m < 4; ++m) {
            bf16x8 a[4];
            #pragma unroll
            for (int k = 0; k < 4; ++k)
                a[k] = ldbf8(&XB[(m*16 + l15)*SRA + k*32 + lg*8]);
            float2 st[4];
            #pragma unroll
            for (int j = 0; j < 4; ++j)
                st[j] = *(const float2*)&stats[(m*16 + lg*4 + j)*2];
            #pragma unroll
            for (int nn = 0; nn < 2; ++nn) {
                f32x4 acc = {0.f,0.f,0.f,0.f};
                #pragma unroll
                for (int k = 0; k < 4; ++k)
                    acc = __builtin_amdgcn_mfma_f32_16x16x32_bf16(a[k], bw1[nn][k], acc, 0, 0, 0);
                #pragma unroll
                for (int j = 0; j < 4; ++j) {
                    float rinv = st[j].y, mean = st[j].x;
                    float t = rinv*acc[j] - rinv*mean*cw1[nn] + bb1[nn];
                    float w = -1.5957691216057308f * (t + 0.044715f*t*t*t);
                    float g = t * __builtin_amdgcn_rcpf(1.f + __expf(w));
                    RA8[(m*16 + lg*4 + j)*SRA + n0 + nn*16 + l15] = f2fp8(g * 8.f);
                }
            }
        }
    }
    __syncthreads();   // B6: t1 x8 in RA8

    // ---- P9: m = t1 @ W2; out = x1(XB) + gmlp*(acc/128 + b2) ----
    {
        const float gmv = gmlp_p[0];
        long bw[2][4];
        float bb[2];
        #pragma unroll
        for (int nn = 0; nn < 2; ++nn) {
            int col = n0 + nn*16 + l15;
            #pragma unroll
            for (int kb = 0; kb < 4; ++kb)
                bw[nn][kb] = ld8(ws8 + W2T8_OFF + col*128 + kb*32 + lg*8);
            bb[nn] = b2[col];
        }
        #pragma unroll
        for (int m = 0; m < 4; ++m) {
            long a[4];
            #pragma unroll
            for (int kb = 0; kb < 4; ++kb)
                a[kb] = ld8(RA8 + (m*16 + l15)*SRA + kb*32 + lg*8);
            #pragma unroll
            for (int nn = 0; nn < 2; ++nn) {
                f32x4 acc = {0.f,0.f,0.f,0.f};
                #pragma unroll
                for (int kb = 0; kb < 4; ++kb)
                    acc = __builtin_amdgcn_mfma_f32_16x16x32_fp8_fp8(a[kb], bw[nn][kb], acc, 0, 0, 0);
                int col = n0 + nn*16 + l15;
                #pragma unroll
                for (int j = 0; j < 4; ++j) {
                    int row = m*16 + lg*4 + j;
                    float x1f = bf2f(XB[row*SRA + col]);
                    outw[row*128 + col] = x1f + gmv * (acc[j] * 0.0078125f + bb[nn]);
                }
            }
        }
    }
}

extern "C" void kernel_launch(void* const* d_in, const int* in_sizes, int n_in,
                              void* d_out, int out_size, void* d_ws, size_t ws_size,
                              hipStream_t stream) {
    const float* x     = (const float*)d_in[0];
    const float* Wq_u  = (const float*)d_in[1];
    const float* Wq_v  = (const float*)d_in[2];
    const float* Wkv_u = (const float*)d_in[3];
    const float* Wkv_v = (const float*)d_in[4];
    const float* kv_b  = (const float*)d_in[5];
    const float* Wo_u  = (const float*)d_in[6];
    const float* Wo_v  = (const float*)d_in[7];
    const float* gamma = (const float*)d_in[8];
    const float* W1    = (const float*)d_in[9];
    const float* b1    = (const float*)d_in[10];
    const float* W2    = (const float*)d_in[11];
    const float* b2    = (const float*)d_in[12];
    const float* gmlp  = (const float*)d_in[13];
    unsigned char* ws8 = (unsigned char*)d_ws;
    float* out = (float*)d_out;

    fam_pre<<<56, 256, 0, stream>>>(Wq_u, Wq_v, Wkv_u, Wkv_v, kv_b, Wo_u, Wo_v, W1, W2, ws8);
    fam_main<<<NWIN, 256, 0, stream>>>(x, ws8, gamma, b1, b2, gmlp, out);
}

// Round 16
// 98.098 us; speedup vs baseline: 1.0018x; 1.0018x over previous
//
#include <hip/hip_runtime.h>

// B=2,G=1024,S=64,L=16,F=8 -> LF=128, ATT=128, RANK=32, HC=32, NH=4. NWIN=2048.
#define NWIN 2048

// ws layout (BYTE offsets). Total 78848 B (under proven 123392 budget).
#define WUT8_OFF 0       // uchar [64][128]   (Wq_u|Wkv_u)^T x16
#define MT8_OFF  8192    // uchar [4][32][32] M^T x256 (incl 1/sqrt32)
#define OT8_OFF  12288   // uchar [128][128]  O^T x128
#define W1T_OFF  28672   // short [128][128]  W1^T bf16 (x1)
#define W2T8_OFF 61440   // uchar [128][128]  W2^T x16
#define CVEC_OFF 77824   // float [128]
#define CSW1_OFF 78336   // float [128]  colsum of W1 (LN2 fold)

typedef __attribute__((ext_vector_type(8))) __bf16 bf16x8;
typedef __attribute__((ext_vector_type(8))) short s16x8;
typedef __attribute__((ext_vector_type(4))) short s16x4;
typedef __attribute__((ext_vector_type(4))) float f32x4;

static __device__ inline short f2bf(float f) {
    __bf16 b = (__bf16)f;
    return __builtin_bit_cast(short, b);
}
static __device__ inline float bf2f(short h) {
    unsigned u = ((unsigned)(unsigned short)h) << 16;
    return __builtin_bit_cast(float, u);
}
static __device__ inline bf16x8 ldbf8(const short* p) {
    return __builtin_bit_cast(bf16x8, *(const s16x8*)p);
}
static __device__ inline unsigned char f2fp8(float v) {
    return (unsigned char)__builtin_amdgcn_cvt_pk_fp8_f32(v, v, 0u, false);
}
static __device__ inline long ld8(const void* p) {
    return *(const long*)p;
}

// ---------------- precompute: fp8 tables (scales exact powers of 2) ----------------
__global__ __launch_bounds__(256) void fam_pre(
    const float* __restrict__ Wq_u, const float* __restrict__ Wq_v,
    const float* __restrict__ Wkv_u, const float* __restrict__ Wkv_v,
    const float* __restrict__ kv_b, const float* __restrict__ Wo_u,
    const float* __restrict__ Wo_v, const float* __restrict__ W1,
    const float* __restrict__ W2, unsigned char* __restrict__ ws8)
{
    const int b = blockIdx.x, tid = threadIdx.x;
    float* cvec = (float*)(ws8 + CVEC_OFF);
    float* csW1 = (float*)(ws8 + CSW1_OFF);
    if (b < 16) {
        __shared__ float Wv[4096];   // Wkv_v v-part [r][c]
        __shared__ float Wu[4096];   // Wo_u [att][u]
        __shared__ float N[4096];    // N[h][u][r]
        for (int i = tid; i < 4096; i += 256) {
            int r = i >> 7, c = i & 127;
            Wv[i] = Wkv_v[r*256 + 128 + c];
            Wu[i] = Wo_u[i];
        }
        __syncthreads();
        for (int i = tid; i < 4096; i += 256) {
            int h = i >> 10, u = (i >> 5) & 31, r = i & 31;
            float acc = 0.f;
            for (int c = 0; c < 32; ++c) acc += Wv[r*128 + h*32 + c] * Wu[(h*32 + c)*32 + u];
            N[i] = acc;
        }
        __syncthreads();
        for (int i = tid; i < 1024; i += 256) {
            int jj = i >> 7, hr = i & 127;
            int j = b*8 + jj, h = hr >> 5, r = hr & 31;
            float acc = 0.f;
            for (int u = 0; u < 32; ++u) acc += N[h*1024 + u*32 + r] * Wo_v[u*128 + j];
            ws8[OT8_OFF + j*128 + hr] = f2fp8(acc * 128.f);
        }
    } else if (b < 32) {
        short* w1t = (short*)(ws8 + W1T_OFF);
        int i0 = (b - 16) * 8;
        for (int t = tid; t < 1024; t += 256) {
            int ii = t >> 7, k = t & 127, i = i0 + ii;
            w1t[i*128 + k] = f2bf(W1[k*128 + i]);
        }
        if (b == 16 && tid < 128) {
            float a = 0.f;
            for (int k = 0; k < 128; ++k) a += W1[k*128 + tid];
            csW1[tid] = a;
        }
    } else if (b < 48) {
        int j0 = (b - 32) * 8;
        for (int t = tid; t < 1024; t += 256) {
            int jj = t >> 7, k = t & 127, j = j0 + jj;
            ws8[W2T8_OFF + j*128 + k] = f2fp8(W2[k*128 + j] * 16.f);
        }
    } else {
        __shared__ float Aq[4096];   // Wq_v [u][128]
        __shared__ float Ak[4096];   // Wkv_v k-part [r][c]
        __shared__ float ov[32];
        for (int i = tid; i < 4096; i += 256) {
            int r = i >> 7, c = i & 127;
            Aq[i] = Wq_v[i];
            Ak[i] = Wkv_v[r*256 + c];
        }
        for (int i = tid; i < 8192; i += 256) {
            int n = i >> 7, k = i & 127;
            float w = (n < 32) ? Wq_u[k*32 + n] : Wkv_u[k*32 + (n - 32)];
            ws8[WUT8_OFF + n*128 + k] = f2fp8(w * 16.f);
        }
        __syncthreads();
        const float sc = 0.17677669529663687f * 256.f;  // 1/sqrt(32) * 256
        for (int i = tid; i < 4096; i += 256) {
            int h = i >> 10, r = (i >> 5) & 31, u = i & 31;
            float acc = 0.f;
            for (int c = 0; c < 32; ++c) acc += Aq[u*128 + h*32 + c] * Ak[r*128 + h*32 + c];
            ws8[MT8_OFF + h*1024 + r*32 + u] = f2fp8(acc * sc);
        }
        if (tid < 32) {
            float a = 0.f;
            for (int att = 0; att < 128; ++att) a += kv_b[128 + att] * Wo_u[att*32 + tid];
            ov[tid] = a;
        }
        __syncthreads();
        if (tid < 128) {
            float a = 0.f;
            for (int u = 0; u < 32; ++u) a += ov[u] * Wo_v[u*128 + tid];
            cvec[tid] = a;
        }
    }
}

// ---------------- main fused kernel: 1 block = 1 window, 4 waves ----------------
// R12 base (65us proven, (256,4), no spill) + stats-only LN2 (R15-verified) +
// LN-folded P8 (R15-verified) + exp2 constant folds. x1v stays in registers.
#define SRA 136   // RA8/XB byte/short stride
#define SHQ 40    // HUQ8/KV8 byte stride
#define SHB 72    // HB8/KVT8 byte stride

#define SM_RA8   0        //  8704  h -> pu -> t1 (fp8 [64][SRA])
#define SM_HUQ8  8704     //  2560  hu_q x4 fp8 [64][SHQ]
#define SM_KV8   11264    //  2560  hu_kv x4 fp8 [64][SHQ]
#define SM_KVT8  13824    //  2304  hu_kv^T x4 fp8 [32][SHB]
#define SM_HB8   16128    // 18432  per head [64][SHB] qt8/P8; later XB bf16 [64][136] (17408) + stats 512
#define SM_STATS (SM_HB8 + 17408)
#define SM_TOTAL 34560

__global__ __launch_bounds__(256, 4) void fam_main(
    const float* __restrict__ x, const unsigned char* __restrict__ ws8,
    const float* __restrict__ gamma, const float* __restrict__ b1,
    const float* __restrict__ b2, const float* __restrict__ gmlp_p,
    float* __restrict__ out)
{
    __shared__ __align__(16) unsigned char SM[SM_TOTAL];
    unsigned char* RA8  = SM + SM_RA8;
    unsigned char* HUQ8 = SM + SM_HUQ8;
    unsigned char* KV8  = SM + SM_KV8;
    unsigned char* KVT8 = SM + SM_KVT8;

    const float* cvec = (const float*)(ws8 + CVEC_OFF);
    const float* csW1 = (const float*)(ws8 + CSW1_OFF);
    const int tid = threadIdx.x;
    const int l   = tid & 63;
    const int wv  = tid >> 6;
    const int l15 = l & 15;
    const int lg  = l >> 4;
    const size_t base = (size_t)blockIdx.x * 8192;
    const float* __restrict__ xw   = x + base;
    float* __restrict__       outw = out + base;
    const int n0 = wv * 32;

    // ---- P1: LN1 -> h (fp8 x1) in RA8 ----
    {
        int s = tid >> 2, c = tid & 3;
        float4 xr1[8];
        float sum = 0.f, sq = 0.f;
        #pragma unroll
        for (int j = 0; j < 8; ++j) {
            xr1[j] = *(const float4*)&xw[s*128 + c*32 + j*4];
            sum += xr1[j].x + xr1[j].y + xr1[j].z + xr1[j].w;
            sq  += xr1[j].x*xr1[j].x + xr1[j].y*xr1[j].y + xr1[j].z*xr1[j].z + xr1[j].w*xr1[j].w;
        }
        sum += __shfl_xor(sum, 1); sq += __shfl_xor(sq, 1);
        sum += __shfl_xor(sum, 2); sq += __shfl_xor(sq, 2);
        float mean = sum * (1.f/128.f);
        float var  = sq * (1.f/128.f) - mean*mean;
        float rinv = rsqrtf(var + 1e-5f);
        #pragma unroll
        for (int j = 0; j < 8; ++j) {
            unsigned w = 0;
            w = __builtin_amdgcn_cvt_pk_fp8_f32((xr1[j].x - mean)*rinv, (xr1[j].y - mean)*rinv, w, false);
            w = __builtin_amdgcn_cvt_pk_fp8_f32((xr1[j].z - mean)*rinv, (xr1[j].w - mean)*rinv, w, true);
            *(unsigned*)&RA8[s*SRA + c*32 + j*4] = w;
        }
    }
    __syncthreads();   // B1

    // ---- P2: [hu_q(32) | hu_kv(32)] = h @ Wu  (fp8 MFMA, acc = hu x16) ----
    {
        long bfr[4];
        #pragma unroll
        for (int kb = 0; kb < 4; ++kb)
            bfr[kb] = ld8(ws8 + WUT8_OFF + (wv*16 + l15)*128 + kb*32 + lg*8);
        #pragma unroll
        for (int m = 0; m < 4; ++m) {
            f32x4 acc = {0.f, 0.f, 0.f, 0.f};
            #pragma unroll
            for (int kb = 0; kb < 4; ++kb) {
                long a = ld8(RA8 + (m*16 + l15)*SRA + kb*32 + lg*8);
                acc = __builtin_amdgcn_mfma_f32_16x16x32_fp8_fp8(a, bfr[kb], acc, 0, 0, 0);
            }
            if (wv < 2) {
                int col = wv*16 + l15;
                #pragma unroll
                for (int j = 0; j < 4; ++j)
                    HUQ8[(m*16 + lg*4 + j)*SHQ + col] = f2fp8(acc[j] * 0.25f);  // hu x4
            } else {
                int u = (wv - 2)*16 + l15;
                #pragma unroll
                for (int j = 0; j < 4; ++j)
                    KV8[(m*16 + lg*4 + j)*SHQ + u] = f2fp8(acc[j] * 0.25f);     // kv x4
                unsigned w = 0;
                w = __builtin_amdgcn_cvt_pk_fp8_f32(acc[0]*0.25f, acc[1]*0.25f, w, false);
                w = __builtin_amdgcn_cvt_pk_fp8_f32(acc[2]*0.25f, acc[3]*0.25f, w, true);
                *(unsigned*)&KVT8[u*SHB + m*16 + lg*4] = w;                     // v x4
            }
        }
    }
    __syncthreads();   // B2

    // ---- P3/P4/P5: per-head attention (h = wv), all fp8 ----
    {
        const int h = wv;
        unsigned char* HB8h = SM + SM_HB8 + h*4608;
        // P3: qt = hu_q @ M_h (acc = qt x1024) -> qt8 = qt x64
        long bm0 = ld8(ws8 + MT8_OFF + h*1024 + l15*32 + lg*8);
        long bm1 = ld8(ws8 + MT8_OFF + h*1024 + (16 + l15)*32 + lg*8);
        #pragma unroll
        for (int m = 0; m < 4; ++m) {
            long aq = ld8(HUQ8 + (m*16 + l15)*SHQ + lg*8);
            f32x4 z = {0.f, 0.f, 0.f, 0.f};
            f32x4 a0 = __builtin_amdgcn_mfma_f32_16x16x32_fp8_fp8(aq, bm0, z, 0, 0, 0);
            f32x4 a1 = __builtin_amdgcn_mfma_f32_16x16x32_fp8_fp8(aq, bm1, z, 0, 0, 0);
            #pragma unroll
            for (int j = 0; j < 4; ++j) {
                int row = (m*16 + lg*4 + j)*SHB;
                HB8h[row + l15]      = f2fp8(a0[j] * 0.0625f);
                HB8h[row + 16 + l15] = f2fp8(a1[j] * 0.0625f);
            }
        }
        // P4: S^T[t][s] (swapped), acc = score x256
        long av[4], bq[4];
        #pragma unroll
        for (int m = 0; m < 4; ++m) av[m] = ld8(KV8 + (m*16 + l15)*SHQ + lg*8);
        #pragma unroll
        for (int n = 0; n < 4; ++n) bq[n] = ld8(HB8h + (n*16 + l15)*SHB + lg*8);
        f32x4 cc[4][4];
        #pragma unroll
        for (int m = 0; m < 4; ++m)
            #pragma unroll
            for (int n = 0; n < 4; ++n) {
                f32x4 z = {0.f, 0.f, 0.f, 0.f};
                cc[m][n] = __builtin_amdgcn_mfma_f32_16x16x32_fp8_fp8(av[m], bq[n], z, 0, 0, 0);
            }
        // softmax over t (exp2 with folded 2^-8 * log2e), P8 = P x64
        const float c1 = 0.0056355275f;  // 2^-8 * log2(e)
        #pragma unroll
        for (int n = 0; n < 4; ++n) {
            float e[4][4];
            float sm = 0.f;
            #pragma unroll
            for (int m = 0; m < 4; ++m)
                #pragma unroll
                for (int j = 0; j < 4; ++j) {
                    e[m][j] = exp2f(fminf(cc[m][n][j] * c1, 43.f));
                    sm += e[m][j];
                }
            sm += __shfl_xor(sm, 16);
            sm += __shfl_xor(sm, 32);
            float rs64 = __builtin_amdgcn_rcpf(sm) * 64.f;
            int srow = (n*16 + l15) * SHB;
            #pragma unroll
            for (int m = 0; m < 4; ++m) {
                unsigned w = 0;
                w = __builtin_amdgcn_cvt_pk_fp8_f32(e[m][0]*rs64, e[m][1]*rs64, w, false);
                w = __builtin_amdgcn_cvt_pk_fp8_f32(e[m][2]*rs64, e[m][3]*rs64, w, true);
                *(unsigned*)&HB8h[srow + m*16 + lg*4] = w;
            }
        }
        // P5: pu = P @ V (acc = pu x256) -> pu8 = pu x8 into RA8
        long a8[4][2], b8[2][2];
        #pragma unroll
        for (int m = 0; m < 4; ++m)
            #pragma unroll
            for (int kb = 0; kb < 2; ++kb)
                a8[m][kb] = ld8(HB8h + (m*16 + l15)*SHB + kb*32 + lg*8);
        #pragma unroll
        for (int nn = 0; nn < 2; ++nn)
            #pragma unroll
            for (int kb = 0; kb < 2; ++kb)
                b8[nn][kb] = ld8(KVT8 + (nn*16 + l15)*SHB + kb*32 + lg*8);
        #pragma unroll
        for (int m = 0; m < 4; ++m)
            #pragma unroll
            for (int nn = 0; nn < 2; ++nn) {
                f32x4 acc = {0.f,0.f,0.f,0.f};
                acc = __builtin_amdgcn_mfma_f32_16x16x32_fp8_fp8(a8[m][0], b8[nn][0], acc, 0, 0, 0);
                acc = __builtin_amdgcn_mfma_f32_16x16x32_fp8_fp8(a8[m][1], b8[nn][1], acc, 0, 0, 0);
                #pragma unroll
                for (int j = 0; j < 4; ++j)
                    RA8[(m*16 + lg*4 + j)*SRA + h*32 + nn*16 + l15] = f2fp8(acc[j] * 0.03125f);
            }
    }
    __syncthreads();   // B3: pu8 in RA8; HB8 dead -> XB

    float x1v[4][2][4];
    short* XB = (short*)(SM + SM_HB8);        // x1 bf16 [64][136] (stays raw)
    float* stats = (float*)(SM + SM_STATS);   // [64][2] mean,rinv

    // ---- P6: upd = pu8 @ O8; x1 = x + gm*(acc/1024 + cv) (regs + XB bf16) ----
    {
        float xr[4][2][4];
        #pragma unroll
        for (int m = 0; m < 4; ++m)
            #pragma unroll
            for (int nn = 0; nn < 2; ++nn)
                #pragma unroll
                for (int j = 0; j < 4; ++j)
                    xr[m][nn][j] = xw[(m*16 + lg*4 + j)*128 + n0 + nn*16 + l15];
        long bo[2][4];
        float cv[2], gm[2];
        #pragma unroll
        for (int nn = 0; nn < 2; ++nn) {
            int col = n0 + nn*16 + l15;
            #pragma unroll
            for (int kb = 0; kb < 4; ++kb)
                bo[nn][kb] = ld8(ws8 + OT8_OFF + col*128 + kb*32 + lg*8);
            cv[nn] = cvec[col];
            gm[nn] = gamma[col];
        }
        f32x4 acc[4][2];
        #pragma unroll
        for (int m = 0; m < 4; ++m)
            #pragma unroll
            for (int nn = 0; nn < 2; ++nn) acc[m][nn] = (f32x4){0.f,0.f,0.f,0.f};
        #pragma unroll
        for (int m = 0; m < 4; ++m) {
            long a[4];
            #pragma unroll
            for (int kb = 0; kb < 4; ++kb)
                a[kb] = ld8(RA8 + (m*16 + l15)*SRA + kb*32 + lg*8);
            #pragma unroll
            for (int kb = 0; kb < 4; ++kb)
                #pragma unroll
                for (int nn = 0; nn < 2; ++nn)
                    acc[m][nn] = __builtin_amdgcn_mfma_f32_16x16x32_fp8_fp8(a[kb], bo[nn][kb], acc[m][nn], 0, 0, 0);
        }
        #pragma unroll
        for (int m = 0; m < 4; ++m)
            #pragma unroll
            for (int nn = 0; nn < 2; ++nn)
                #pragma unroll
                for (int j = 0; j < 4; ++j) {
                    int row = m*16 + lg*4 + j;
                    float v = xr[m][nn][j] + gm[nn] * (acc[m][nn][j] * 9.765625e-4f + cv[nn]);
                    x1v[m][nn][j] = v;
                    XB[row*SRA + n0 + nn*16 + l15] = f2bf(v);
                }
    }
    __syncthreads();   // B4: x1 bf16 in XB complete

    // ---- P7: LN2 stats only (no XB rewrite) ----
    {
        int s = tid >> 2, c = tid & 3;
        float sum = 0.f, sq = 0.f;
        #pragma unroll
        for (int jj = 0; jj < 8; ++jj) {
            s16x4 hv = *(const s16x4*)&XB[s*SRA + c*32 + jj*4];
            #pragma unroll
            for (int e = 0; e < 4; ++e) {
                float f = bf2f(hv[e]);
                sum += f; sq += f*f;
            }
        }
        sum += __shfl_xor(sum, 1); sq += __shfl_xor(sq, 1);
        sum += __shfl_xor(sum, 2); sq += __shfl_xor(sq, 2);
        if (c == 0) {
            float mean = sum * (1.f/128.f);
            float var  = sq * (1.f/128.f) - mean*mean;
            stats[s*2]     = mean;
            stats[s*2 + 1] = rsqrtf(var + 1e-5f);
        }
    }
    __syncthreads();   // B5: stats ready; XB holds raw x1

    // ---- P8: t1 = gelu(LNfold(x1 @ W1)) -> t1 x8 fp8 into RA8 ----
    {
        const short* W1t = (const short*)(ws8 + W1T_OFF);
        bf16x8 bw1[2][4];
        float bb1[2], cw1[2];
        #pragma unroll
        for (int nn = 0; nn < 2; ++nn) {
            int col = n0 + nn*16 + l15;
            #pragma unroll
            for (int k = 0; k < 4; ++k)
                bw1[nn][k] = ldbf8(&W1t[col*128 + k*32 + lg*8]);
            bb1[nn] = b1[col];
            cw1[nn] = csW1[col];
        }
        #pragma unroll
        for (int m = 0; m < 4; ++m) {
            bf16x8 a[4];
            #pragma unroll
            for (int k = 0; k < 4; ++k)
                a[k] = ldbf8(&XB[(m*16 + l15)*SRA + k*32 + lg*8]);
            float2 st[4];
            #pragma unroll
            for (int j = 0; j < 4; ++j)
                st[j] = *(const float2*)&stats[(m*16 + lg*4 + j)*2];
            #pragma unroll
            for (int nn = 0; nn < 2; ++nn) {
                f32x4 acc = {0.f,0.f,0.f,0.f};
                #pragma unroll
                for (int k = 0; k < 4; ++k)
                    acc = __builtin_amdgcn_mfma_f32_16x16x32_bf16(a[k], bw1[nn][k], acc, 0, 0, 0);
                #pragma unroll
                for (int j = 0; j < 4; ++j) {
                    float rinv = st[j].y, mean = st[j].x;
                    float t = rinv*acc[j] - rinv*mean*cw1[nn] + bb1[nn];
                    // gelu(t) = t*sigmoid(1.5958(t+0.044715t^3)); exp2-folded
                    float u2 = t*t;
                    float p = fmaf(-0.1029417f, u2, -2.3021622f);
                    float g = t * __builtin_amdgcn_rcpf(1.f + exp2f(t*p));
                    RA8[(m*16 + lg*4 + j)*SRA + n0 + nn*16 + l15] = f2fp8(g * 8.f);
                }
            }
        }
    }
    __syncthreads();   // B6: t1 x8 in RA8

    // ---- P9: m = t1 @ W2 (acc = m x128); out = x1(reg) + gmlp*(acc/128 + b2) ----
    {
        const float gmv = gmlp_p[0];
        long bw[2][4];
        float bb[2];
        #pragma unroll
        for (int nn = 0; nn < 2; ++nn) {
            int col = n0 + nn*16 + l15;
            #pragma unroll
            for (int kb = 0; kb < 4; ++kb)
                bw[nn][kb] = ld8(ws8 + W2T8_OFF + col*128 + kb*32 + lg*8);
            bb[nn] = b2[col];
        }
        #pragma unroll
        for (int m = 0; m < 4; ++m) {
            long a[4];
            #pragma unroll
            for (int kb = 0; kb < 4; ++kb)
                a[kb] = ld8(RA8 + (m*16 + l15)*SRA + kb*32 + lg*8);
            #pragma unroll
            for (int nn = 0; nn < 2; ++nn) {
                f32x4 acc = {0.f,0.f,0.f,0.f};
                #pragma unroll
                for (int kb = 0; kb < 4; ++kb)
                    acc = __builtin_amdgcn_mfma_f32_16x16x32_fp8_fp8(a[kb], bw[nn][kb], acc, 0, 0, 0);
                #pragma unroll
                for (int j = 0; j < 4; ++j)
                    outw[(m*16 + lg*4 + j)*128 + n0 + nn*16 + l15] =
                        x1v[m][nn][j] + gmv * (acc[j] * 0.0078125f + bb[nn]);
            }
        }
    }
}

extern "C" void kernel_launch(void* const* d_in, const int* in_sizes, int n_in,
                              void* d_out, int out_size, void* d_ws, size_t ws_size,
                              hipStream_t stream) {
    const float* x     = (const float*)d_in[0];
    const float* Wq_u  = (const float*)d_in[1];
    const float* Wq_v  = (const float*)d_in[2];
    const float* Wkv_u = (const float*)d_in[3];
    const float* Wkv_v = (const float*)d_in[4];
    const float* kv_b  = (const float*)d_in[5];
    const float* Wo_u  = (const float*)d_in[6];
    const float* Wo_v  = (const float*)d_in[7];
    const float* gamma = (const float*)d_in[8];
    const float* W1    = (const float*)d_in[9];
    const float* b1    = (const float*)d_in[10];
    const float* W2    = (const float*)d_in[11];
    const float* b2    = (const float*)d_in[12];
    const float* gmlp  = (const float*)d_in[13];
    unsigned char* ws8 = (unsigned char*)d_ws;
    float* out = (float*)d_out;

    fam_pre<<<49, 256, 0, stream>>>(Wq_u, Wq_v, Wkv_u, Wkv_v, kv_b, Wo_u, Wo_v, W1, W2, ws8);
    fam_main<<<NWIN, 256, 0, stream>>>(x, ws8, gamma, b1, b2, gmlp, out);
}

// Round 17
// 94.155 us; speedup vs baseline: 1.0438x; 1.0419x over previous
//
#include <hip/hip_runtime.h>

// B=2,G=1024,S=64,L=16,F=8 -> LF=128, ATT=128, RANK=32, HC=32, NH=4. NWIN=2048.
#define NWIN 2048

// ws layout (BYTE offsets). Total 78336 B.
#define WUT8_OFF 0       // uchar [64][128]   (Wq_u|Wkv_u)^T x16
#define MT8_OFF  8192    // uchar [4][32][32] M^T x256 (incl 1/sqrt32)
#define OT8_OFF  12288   // uchar [128][128]  O^T x128
#define W1T_OFF  28672   // short [128][128]  W1^T bf16 (x1)
#define W2T8_OFF 61440   // uchar [128][128]  W2^T x16
#define CVEC_OFF 77824   // float [128]

typedef __attribute__((ext_vector_type(8))) __bf16 bf16x8;
typedef __attribute__((ext_vector_type(8))) short s16x8;
typedef __attribute__((ext_vector_type(4))) short s16x4;
typedef __attribute__((ext_vector_type(4))) float f32x4;

static __device__ inline short f2bf(float f) {
    __bf16 b = (__bf16)f;
    return __builtin_bit_cast(short, b);
}
static __device__ inline float bf2f(short h) {
    unsigned u = ((unsigned)(unsigned short)h) << 16;
    return __builtin_bit_cast(float, u);
}
static __device__ inline bf16x8 ldbf8(const short* p) {
    return __builtin_bit_cast(bf16x8, *(const s16x8*)p);
}
static __device__ inline unsigned char f2fp8(float v) {
    return (unsigned char)__builtin_amdgcn_cvt_pk_fp8_f32(v, v, 0u, false);
}
static __device__ inline long ld8(const void* p) {
    return *(const long*)p;
}

// ---------------- precompute: fp8 tables (scales are exact powers of 2) ----------------
__global__ __launch_bounds__(256) void fam_pre(
    const float* __restrict__ Wq_u, const float* __restrict__ Wq_v,
    const float* __restrict__ Wkv_u, const float* __restrict__ Wkv_v,
    const float* __restrict__ kv_b, const float* __restrict__ Wo_u,
    const float* __restrict__ Wo_v, const float* __restrict__ W1,
    const float* __restrict__ W2, unsigned char* __restrict__ ws8)
{
    const int b = blockIdx.x, tid = threadIdx.x;
    float* cvec = (float*)(ws8 + CVEC_OFF);
    if (b < 16) {
        __shared__ float Wv[4096];   // Wkv_v v-part [r][c]
        __shared__ float Wu[4096];   // Wo_u [att][u]
        __shared__ float N[4096];    // N[h][u][r]
        for (int i = tid; i < 4096; i += 256) {
            int r = i >> 7, c = i & 127;
            Wv[i] = Wkv_v[r*256 + 128 + c];
            Wu[i] = Wo_u[i];
        }
        __syncthreads();
        for (int i = tid; i < 4096; i += 256) {
            int h = i >> 10, u = (i >> 5) & 31, r = i & 31;
            float acc = 0.f;
            for (int c = 0; c < 32; ++c) acc += Wv[r*128 + h*32 + c] * Wu[(h*32 + c)*32 + u];
            N[i] = acc;
        }
        __syncthreads();
        for (int i = tid; i < 1024; i += 256) {
            int jj = i >> 7, hr = i & 127;
            int j = b*8 + jj, h = hr >> 5, r = hr & 31;
            float acc = 0.f;
            for (int u = 0; u < 32; ++u) acc += N[h*1024 + u*32 + r] * Wo_v[u*128 + j];
            ws8[OT8_OFF + j*128 + hr] = f2fp8(acc * 128.f);
        }
    } else if (b < 32) {
        short* w1t = (short*)(ws8 + W1T_OFF);
        int i0 = (b - 16) * 8;
        for (int t = tid; t < 1024; t += 256) {
            int ii = t >> 7, k = t & 127, i = i0 + ii;
            w1t[i*128 + k] = f2bf(W1[k*128 + i]);
        }
    } else if (b < 48) {
        int j0 = (b - 32) * 8;
        for (int t = tid; t < 1024; t += 256) {
            int jj = t >> 7, k = t & 127, j = j0 + jj;
            ws8[W2T8_OFF + j*128 + k] = f2fp8(W2[k*128 + j] * 16.f);
        }
    } else {
        __shared__ float Aq[4096];   // Wq_v [u][128]
        __shared__ float Ak[4096];   // Wkv_v k-part [r][c]
        __shared__ float ov[32];
        for (int i = tid; i < 4096; i += 256) {
            int r = i >> 7, c = i & 127;
            Aq[i] = Wq_v[i];
            Ak[i] = Wkv_v[r*256 + c];
        }
        for (int i = tid; i < 8192; i += 256) {
            int n = i >> 7, k = i & 127;
            float w = (n < 32) ? Wq_u[k*32 + n] : Wkv_u[k*32 + (n - 32)];
            ws8[WUT8_OFF + n*128 + k] = f2fp8(w * 16.f);
        }
        __syncthreads();
        const float sc = 0.17677669529663687f * 256.f;  // 1/sqrt(32) * 256
        for (int i = tid; i < 4096; i += 256) {
            int h = i >> 10, r = (i >> 5) & 31, u = i & 31;
            float acc = 0.f;
            for (int c = 0; c < 32; ++c) acc += Aq[u*128 + h*32 + c] * Ak[r*128 + h*32 + c];
            ws8[MT8_OFF + h*1024 + r*32 + u] = f2fp8(acc * sc);
        }
        if (tid < 32) {
            float a = 0.f;
            for (int att = 0; att < 128; ++att) a += kv_b[128 + att] * Wo_u[att*32 + tid];
            ov[tid] = a;
        }
        __syncthreads();
        if (tid < 128) {
            float a = 0.f;
            for (int u = 0; u < 32; ++u) a += ov[u] * Wo_v[u*128 + tid];
            cvec[tid] = a;
        }
    }
}

// ---------------- main fused kernel: 1 block = 1 window, 4 waves ----------------
// EXACT R12 champion (65us, (256,4), no spill) + exp2 constant folds only.
// Scale ledger: h x1 | Wu x16 | hu x4 | M x256 | qt x64 | score acc x256 |
//               P x64 | V x4 | pu x8 | O x128 | t1 x8 | W2 x16.
#define SRA 136   // RA8/XB byte/short stride
#define SHQ 40    // HUQ8/KV8 byte stride
#define SHB 72    // HB8/KVT8 byte stride

#define SM_RA8   0        //  8704  h -> pu -> t1 (fp8 [64][SRA])
#define SM_HUQ8  8704     //  2560  hu_q x4 fp8 [64][SHQ]
#define SM_KV8   11264    //  2560  hu_kv x4 fp8 [64][SHQ] (A of scores)
#define SM_KVT8  13824    //  2304  hu_kv^T x4 fp8 [32][SHB] (B of PV)
#define SM_HB8   16128    // 18432  per head [64][SHB]: qt8 then P8; later XB = x1/h2 bf16 [64][136]
#define SM_TOTAL 34560

__global__ __launch_bounds__(256, 4) void fam_main(
    const float* __restrict__ x, const unsigned char* __restrict__ ws8,
    const float* __restrict__ gamma, const float* __restrict__ b1,
    const float* __restrict__ b2, const float* __restrict__ gmlp_p,
    float* __restrict__ out)
{
    __shared__ __align__(16) unsigned char SM[SM_TOTAL];
    unsigned char* RA8  = SM + SM_RA8;
    unsigned char* HUQ8 = SM + SM_HUQ8;
    unsigned char* KV8  = SM + SM_KV8;
    unsigned char* KVT8 = SM + SM_KVT8;

    const float* cvec = (const float*)(ws8 + CVEC_OFF);
    const int tid = threadIdx.x;
    const int l   = tid & 63;
    const int wv  = tid >> 6;
    const int l15 = l & 15;
    const int lg  = l >> 4;
    const size_t base = (size_t)blockIdx.x * 8192;
    const float* __restrict__ xw   = x + base;
    float* __restrict__       outw = out + base;
    const int n0 = wv * 32;

    // ---- P1: LN1 -> h (fp8 x1) in RA8 ----
    {
        int s = tid >> 2, c = tid & 3;
        float4 xr1[8];
        float sum = 0.f, sq = 0.f;
        #pragma unroll
        for (int j = 0; j < 8; ++j) {
            xr1[j] = *(const float4*)&xw[s*128 + c*32 + j*4];
            sum += xr1[j].x + xr1[j].y + xr1[j].z + xr1[j].w;
            sq  += xr1[j].x*xr1[j].x + xr1[j].y*xr1[j].y + xr1[j].z*xr1[j].z + xr1[j].w*xr1[j].w;
        }
        sum += __shfl_xor(sum, 1); sq += __shfl_xor(sq, 1);
        sum += __shfl_xor(sum, 2); sq += __shfl_xor(sq, 2);
        float mean = sum * (1.f/128.f);
        float var  = sq * (1.f/128.f) - mean*mean;
        float rinv = rsqrtf(var + 1e-5f);
        #pragma unroll
        for (int j = 0; j < 8; ++j) {
            unsigned w = 0;
            w = __builtin_amdgcn_cvt_pk_fp8_f32((xr1[j].x - mean)*rinv, (xr1[j].y - mean)*rinv, w, false);
            w = __builtin_amdgcn_cvt_pk_fp8_f32((xr1[j].z - mean)*rinv, (xr1[j].w - mean)*rinv, w, true);
            *(unsigned*)&RA8[s*SRA + c*32 + j*4] = w;
        }
    }
    __syncthreads();   // B1

    // ---- P2: [hu_q(32) | hu_kv(32)] = h @ Wu  (fp8 MFMA, acc = hu x16) ----
    {
        long bfr[4];
        #pragma unroll
        for (int kb = 0; kb < 4; ++kb)
            bfr[kb] = ld8(ws8 + WUT8_OFF + (wv*16 + l15)*128 + kb*32 + lg*8);
        #pragma unroll
        for (int m = 0; m < 4; ++m) {
            f32x4 acc = {0.f, 0.f, 0.f, 0.f};
            #pragma unroll
            for (int kb = 0; kb < 4; ++kb) {
                long a = ld8(RA8 + (m*16 + l15)*SRA + kb*32 + lg*8);
                acc = __builtin_amdgcn_mfma_f32_16x16x32_fp8_fp8(a, bfr[kb], acc, 0, 0, 0);
            }
            if (wv < 2) {
                int col = wv*16 + l15;
                #pragma unroll
                for (int j = 0; j < 4; ++j)
                    HUQ8[(m*16 + lg*4 + j)*SHQ + col] = f2fp8(acc[j] * 0.25f);  // hu x4
            } else {
                int u = (wv - 2)*16 + l15;
                #pragma unroll
                for (int j = 0; j < 4; ++j)
                    KV8[(m*16 + lg*4 + j)*SHQ + u] = f2fp8(acc[j] * 0.25f);     // kv x4
                unsigned w = 0;
                w = __builtin_amdgcn_cvt_pk_fp8_f32(acc[0]*0.25f, acc[1]*0.25f, w, false);
                w = __builtin_amdgcn_cvt_pk_fp8_f32(acc[2]*0.25f, acc[3]*0.25f, w, true);
                *(unsigned*)&KVT8[u*SHB + m*16 + lg*4] = w;                     // v x4
            }
        }
    }
    __syncthreads();   // B2

    // ---- P3/P4/P5: per-head attention, wave-local (h = wv), all fp8 ----
    {
        const int h = wv;
        unsigned char* HB8h = SM + SM_HB8 + h*4608;
        // P3: qt = hu_q @ M_h  (acc = qt x1024) -> qt8 = qt x64
        long bm0 = ld8(ws8 + MT8_OFF + h*1024 + l15*32 + lg*8);
        long bm1 = ld8(ws8 + MT8_OFF + h*1024 + (16 + l15)*32 + lg*8);
        #pragma unroll
        for (int m = 0; m < 4; ++m) {
            long aq = ld8(HUQ8 + (m*16 + l15)*SHQ + lg*8);
            f32x4 z = {0.f, 0.f, 0.f, 0.f};
            f32x4 a0 = __builtin_amdgcn_mfma_f32_16x16x32_fp8_fp8(aq, bm0, z, 0, 0, 0);
            f32x4 a1 = __builtin_amdgcn_mfma_f32_16x16x32_fp8_fp8(aq, bm1, z, 0, 0, 0);
            #pragma unroll
            for (int j = 0; j < 4; ++j) {
                int row = (m*16 + lg*4 + j)*SHB;
                HB8h[row + l15]      = f2fp8(a0[j] * 0.0625f);
                HB8h[row + 16 + l15] = f2fp8(a1[j] * 0.0625f);
            }
        }
        // P4: S^T[t][s] (swapped), acc = score x256
        long av[4], bq[4];
        #pragma unroll
        for (int m = 0; m < 4; ++m) av[m] = ld8(KV8 + (m*16 + l15)*SHQ + lg*8);
        #pragma unroll
        for (int n = 0; n < 4; ++n) bq[n] = ld8(HB8h + (n*16 + l15)*SHB + lg*8);
        f32x4 cc[4][4];
        #pragma unroll
        for (int m = 0; m < 4; ++m)
            #pragma unroll
            for (int n = 0; n < 4; ++n) {
                f32x4 z = {0.f, 0.f, 0.f, 0.f};
                cc[m][n] = __builtin_amdgcn_mfma_f32_16x16x32_fp8_fp8(av[m], bq[n], z, 0, 0, 0);
            }
        // softmax over t (no max-reduce; scores tiny); exp2 with folded 2^-8*log2e
        const float c1 = 0.0056355275f;  // 2^-8 * log2(e)
        #pragma unroll
        for (int n = 0; n < 4; ++n) {
            float e[4][4];
            float sm = 0.f;
            #pragma unroll
            for (int m = 0; m < 4; ++m)
                #pragma unroll
                for (int j = 0; j < 4; ++j) {
                    e[m][j] = exp2f(fminf(cc[m][n][j] * c1, 43.f));
                    sm += e[m][j];
                }
            sm += __shfl_xor(sm, 16);
            sm += __shfl_xor(sm, 32);
            float rs64 = __builtin_amdgcn_rcpf(sm) * 64.f;
            int srow = (n*16 + l15) * SHB;
            #pragma unroll
            for (int m = 0; m < 4; ++m) {
                unsigned w = 0;
                w = __builtin_amdgcn_cvt_pk_fp8_f32(e[m][0]*rs64, e[m][1]*rs64, w, false);
                w = __builtin_amdgcn_cvt_pk_fp8_f32(e[m][2]*rs64, e[m][3]*rs64, w, true);
                *(unsigned*)&HB8h[srow + m*16 + lg*4] = w;
            }
        }
        // P5: pu = P @ V, acc = pu x256 -> pu8 = pu x8 into RA8
        long a8[4][2], b8[2][2];
        #pragma unroll
        for (int m = 0; m < 4; ++m)
            #pragma unroll
            for (int kb = 0; kb < 2; ++kb)
                a8[m][kb] = ld8(HB8h + (m*16 + l15)*SHB + kb*32 + lg*8);
        #pragma unroll
        for (int nn = 0; nn < 2; ++nn)
            #pragma unroll
            for (int kb = 0; kb < 2; ++kb)
                b8[nn][kb] = ld8(KVT8 + (nn*16 + l15)*SHB + kb*32 + lg*8);
        #pragma unroll
        for (int m = 0; m < 4; ++m)
            #pragma unroll
            for (int nn = 0; nn < 2; ++nn) {
                f32x4 acc = {0.f,0.f,0.f,0.f};
                acc = __builtin_amdgcn_mfma_f32_16x16x32_fp8_fp8(a8[m][0], b8[nn][0], acc, 0, 0, 0);
                acc = __builtin_amdgcn_mfma_f32_16x16x32_fp8_fp8(a8[m][1], b8[nn][1], acc, 0, 0, 0);
                #pragma unroll
                for (int j = 0; j < 4; ++j)
                    RA8[(m*16 + lg*4 + j)*SRA + h*32 + nn*16 + l15] = f2fp8(acc[j] * 0.03125f);
            }
    }
    __syncthreads();   // B3: pu8 in RA8 complete; HB8 dead -> XB

    float x1v[4][2][4];
    short* XB = (short*)(SM + SM_HB8);   // x1/h2 bf16 [64][136]

    // ---- P6: upd = pu8 @ O8 (acc = upd x1024); x1 = x + gm*(acc/1024 + cv) ----
    {
        float xr[4][2][4];
        #pragma unroll
        for (int m = 0; m < 4; ++m)
            #pragma unroll
            for (int nn = 0; nn < 2; ++nn)
                #pragma unroll
                for (int j = 0; j < 4; ++j)
                    xr[m][nn][j] = xw[(m*16 + lg*4 + j)*128 + n0 + nn*16 + l15];
        long bo[2][4];
        float cv[2], gm[2];
        #pragma unroll
        for (int nn = 0; nn < 2; ++nn) {
            int col = n0 + nn*16 + l15;
            #pragma unroll
            for (int kb = 0; kb < 4; ++kb)
                bo[nn][kb] = ld8(ws8 + OT8_OFF + col*128 + kb*32 + lg*8);
            cv[nn] = cvec[col];
            gm[nn] = gamma[col];
        }
        f32x4 acc[4][2];
        #pragma unroll
        for (int m = 0; m < 4; ++m)
            #pragma unroll
            for (int nn = 0; nn < 2; ++nn) acc[m][nn] = (f32x4){0.f,0.f,0.f,0.f};
        #pragma unroll
        for (int m = 0; m < 4; ++m) {
            long a[4];
            #pragma unroll
            for (int kb = 0; kb < 4; ++kb)
                a[kb] = ld8(RA8 + (m*16 + l15)*SRA + kb*32 + lg*8);
            #pragma unroll
            for (int kb = 0; kb < 4; ++kb)
                #pragma unroll
                for (int nn = 0; nn < 2; ++nn)
                    acc[m][nn] = __builtin_amdgcn_mfma_f32_16x16x32_fp8_fp8(a[kb], bo[nn][kb], acc[m][nn], 0, 0, 0);
        }
        // XB does not alias RA8: no interior barrier needed
        #pragma unroll
        for (int m = 0; m < 4; ++m)
            #pragma unroll
            for (int nn = 0; nn < 2; ++nn)
                #pragma unroll
                for (int j = 0; j < 4; ++j) {
                    int row = m*16 + lg*4 + j;
                    float v = xr[m][nn][j] + gm[nn] * (acc[m][nn][j] * 9.765625e-4f + cv[nn]);
                    x1v[m][nn][j] = v;
                    XB[row*SRA + n0 + nn*16 + l15] = f2bf(v);
                }
    }
    __syncthreads();   // B4: x1 bf16 in XB complete

    // ---- P7: LN2 on XB in place (bf16, proven) ----
    {
        int s = tid >> 2, c = tid & 3;
        float sum = 0.f, sq = 0.f;
        #pragma unroll
        for (int jj = 0; jj < 8; ++jj) {
            s16x4 hv = *(const s16x4*)&XB[s*SRA + c*32 + jj*4];
            #pragma unroll
            for (int e = 0; e < 4; ++e) {
                float f = bf2f(hv[e]);
                sum += f; sq += f*f;
            }
        }
        sum += __shfl_xor(sum, 1); sq += __shfl_xor(sq, 1);
        sum += __shfl_xor(sum, 2); sq += __shfl_xor(sq, 2);
        float mean = sum * (1.f/128.f);
        float var  = sq * (1.f/128.f) - mean*mean;
        float rinv = rsqrtf(var + 1e-5f);
        #pragma unroll
        for (int jj = 0; jj < 8; ++jj) {
            s16x4 hv = *(const s16x4*)&XB[s*SRA + c*32 + jj*4];
            s16x4 ov;
            #pragma unroll
            for (int e = 0; e < 4; ++e) ov[e] = f2bf((bf2f(hv[e]) - mean) * rinv);
            *(s16x4*)&XB[s*SRA + c*32 + jj*4] = ov;
        }
    }
    __syncthreads();   // B5: h2 in XB

    // ---- P8: t1 = gelu(h2 @ W1 + b1) (bf16 MFMA) -> t1 x8 fp8 into RA8 ----
    {
        const short* W1t = (const short*)(ws8 + W1T_OFF);
        bf16x8 bw1[2][4];
        float bb1[2];
        #pragma unroll
        for (int nn = 0; nn < 2; ++nn) {
            #pragma unroll
            for (int k = 0; k < 4; ++k)
                bw1[nn][k] = ldbf8(&((const short*)(ws8 + W1T_OFF))[(n0 + nn*16 + l15)*128 + k*32 + lg*8]);
            bb1[nn] = b1[n0 + nn*16 + l15];
        }
        (void)W1t;
        #pragma unroll
        for (int m = 0; m < 4; ++m) {
            bf16x8 a[4];
            #pragma unroll
            for (int k = 0; k < 4; ++k)
                a[k] = ldbf8(&XB[(m*16 + l15)*SRA + k*32 + lg*8]);
            #pragma unroll
            for (int nn = 0; nn < 2; ++nn) {
                f32x4 acc = {0.f,0.f,0.f,0.f};
                #pragma unroll
                for (int k = 0; k < 4; ++k)
                    acc = __builtin_amdgcn_mfma_f32_16x16x32_bf16(a[k], bw1[nn][k], acc, 0, 0, 0);
                #pragma unroll
                for (int j = 0; j < 4; ++j) {
                    float t = acc[j] + bb1[nn];
                    // gelu(t) = t*sigmoid(1.5958(t+0.044715t^3)); exp2-folded constants
                    float u2 = t*t;
                    float p = fmaf(-0.1029417f, u2, -2.3021622f);
                    float g = t * __builtin_amdgcn_rcpf(1.f + exp2f(t*p));
                    RA8[(m*16 + lg*4 + j)*SRA + n0 + nn*16 + l15] = f2fp8(g * 8.f);
                }
            }
        }
    }
    __syncthreads();   // B6: t1 x8 in RA8

    // ---- P9: m = t1 @ W2 (acc = m x128); out = x1(reg) + gmlp*(acc/128 + b2) ----
    {
        const float gmv = gmlp_p[0];
        long bw[2][4];
        float bb[2];
        #pragma unroll
        for (int nn = 0; nn < 2; ++nn) {
            int col = n0 + nn*16 + l15;
            #pragma unroll
            for (int kb = 0; kb < 4; ++kb)
                bw[nn][kb] = ld8(ws8 + W2T8_OFF + col*128 + kb*32 + lg*8);
            bb[nn] = b2[col];
        }
        #pragma unroll
        for (int m = 0; m < 4; ++m) {
            long a[4];
            #pragma unroll
            for (int kb = 0; kb < 4; ++kb)
                a[kb] = ld8(RA8 + (m*16 + l15)*SRA + kb*32 + lg*8);
            #pragma unroll
            for (int nn = 0; nn < 2; ++nn) {
                f32x4 acc = {0.f,0.f,0.f,0.f};
                #pragma unroll
                for (int kb = 0; kb < 4; ++kb)
                    acc = __builtin_amdgcn_mfma_f32_16x16x32_fp8_fp8(a[kb], bw[nn][kb], acc, 0, 0, 0);
                #pragma unroll
                for (int j = 0; j < 4; ++j)
                    outw[(m*16 + lg*4 + j)*128 + n0 + nn*16 + l15] =
                        x1v[m][nn][j] + gmv * (acc[j] * 0.0078125f + bb[nn]);
            }
        }
    }
}

extern "C" void kernel_launch(void* const* d_in, const int* in_sizes, int n_in,
                              void* d_out, int out_size, void* d_ws, size_t ws_size,
                              hipStream_t stream) {
    const float* x     = (const float*)d_in[0];
    const float* Wq_u  = (const float*)d_in[1];
    const float* Wq_v  = (const float*)d_in[2];
    const float* Wkv_u = (const float*)d_in[3];
    const float* Wkv_v = (const float*)d_in[4];
    const float* kv_b  = (const float*)d_in[5];
    const float* Wo_u  = (const float*)d_in[6];
    const float* Wo_v  = (const float*)d_in[7];
    const float* gamma = (const float*)d_in[8];
    const float* W1    = (const float*)d_in[9];
    const float* b1    = (const float*)d_in[10];
    const float* W2    = (const float*)d_in[11];
    const float* b2    = (const float*)d_in[12];
    const float* gmlp  = (const float*)d_in[13];
    unsigned char* ws8 = (unsigned char*)d_ws;
    float* out = (float*)d_out;

    fam_pre<<<49, 256, 0, stream>>>(Wq_u, Wq_v, Wkv_u, Wkv_v, kv_b, Wo_u, Wo_v, W1, W2, ws8);
    fam_main<<<NWIN, 256, 0, stream>>>(x, ws8, gamma, b1, b2, gmlp, out);
}

// Round 18
// 93.361 us; speedup vs baseline: 1.0526x; 1.0085x over previous
//
#include <hip/hip_runtime.h>

// B=2,G=1024,S=64,L=16,F=8 -> LF=128, ATT=128, RANK=32, HC=32, NH=4. NWIN=2048.
#define NWIN 2048

// ws layout (BYTE offsets). Total 78336 B.
#define WUT8_OFF 0       // uchar [64][128]   (Wq_u|Wkv_u)^T x16
#define MT8_OFF  8192    // uchar [4][32][32] M^T x256 (incl 1/sqrt32)
#define OT8_OFF  12288   // uchar [128][128]  O^T x128
#define W1T_OFF  28672   // short [128][128]  W1^T bf16 (x1)
#define W2T8_OFF 61440   // uchar [128][128]  W2^T x16
#define CVEC_OFF 77824   // float [128]

typedef __attribute__((ext_vector_type(8))) __bf16 bf16x8;
typedef __attribute__((ext_vector_type(8))) short s16x8;
typedef __attribute__((ext_vector_type(4))) short s16x4;
typedef __attribute__((ext_vector_type(4))) float f32x4;

static __device__ inline short f2bf(float f) {
    __bf16 b = (__bf16)f;
    return __builtin_bit_cast(short, b);
}
static __device__ inline float bf2f(short h) {
    unsigned u = ((unsigned)(unsigned short)h) << 16;
    return __builtin_bit_cast(float, u);
}
static __device__ inline bf16x8 ldbf8(const short* p) {
    return __builtin_bit_cast(bf16x8, *(const s16x8*)p);
}
static __device__ inline unsigned char f2fp8(float v) {
    return (unsigned char)__builtin_amdgcn_cvt_pk_fp8_f32(v, v, 0u, false);
}
static __device__ inline long ld8(const void* p) {
    return *(const long*)p;
}

// ---------------- precompute: fp8 tables (scales are exact powers of 2) ----------------
__global__ __launch_bounds__(256) void fam_pre(
    const float* __restrict__ Wq_u, const float* __restrict__ Wq_v,
    const float* __restrict__ Wkv_u, const float* __restrict__ Wkv_v,
    const float* __restrict__ kv_b, const float* __restrict__ Wo_u,
    const float* __restrict__ Wo_v, const float* __restrict__ W1,
    const float* __restrict__ W2, unsigned char* __restrict__ ws8)
{
    const int b = blockIdx.x, tid = threadIdx.x;
    float* cvec = (float*)(ws8 + CVEC_OFF);
    if (b < 16) {
        __shared__ float Wv[4096];   // Wkv_v v-part [r][c]
        __shared__ float Wu[4096];   // Wo_u [att][u]
        __shared__ float N[4096];    // N[h][u][r]
        for (int i = tid; i < 4096; i += 256) {
            int r = i >> 7, c = i & 127;
            Wv[i] = Wkv_v[r*256 + 128 + c];
            Wu[i] = Wo_u[i];
        }
        __syncthreads();
        for (int i = tid; i < 4096; i += 256) {
            int h = i >> 10, u = (i >> 5) & 31, r = i & 31;
            float acc = 0.f;
            for (int c = 0; c < 32; ++c) acc += Wv[r*128 + h*32 + c] * Wu[(h*32 + c)*32 + u];
            N[i] = acc;
        }
        __syncthreads();
        for (int i = tid; i < 1024; i += 256) {
            int jj = i >> 7, hr = i & 127;
            int j = b*8 + jj, h = hr >> 5, r = hr & 31;
            float acc = 0.f;
            for (int u = 0; u < 32; ++u) acc += N[h*1024 + u*32 + r] * Wo_v[u*128 + j];
            ws8[OT8_OFF + j*128 + hr] = f2fp8(acc * 128.f);
        }
    } else if (b < 32) {
        short* w1t = (short*)(ws8 + W1T_OFF);
        int i0 = (b - 16) * 8;
        for (int t = tid; t < 1024; t += 256) {
            int ii = t >> 7, k = t & 127, i = i0 + ii;
            w1t[i*128 + k] = f2bf(W1[k*128 + i]);
        }
    } else if (b < 48) {
        int j0 = (b - 32) * 8;
        for (int t = tid; t < 1024; t += 256) {
            int jj = t >> 7, k = t & 127, j = j0 + jj;
            ws8[W2T8_OFF + j*128 + k] = f2fp8(W2[k*128 + j] * 16.f);
        }
    } else {
        __shared__ float Aq[4096];   // Wq_v [u][128]
        __shared__ float Ak[4096];   // Wkv_v k-part [r][c]
        __shared__ float ov[32];
        for (int i = tid; i < 4096; i += 256) {
            int r = i >> 7, c = i & 127;
            Aq[i] = Wq_v[i];
            Ak[i] = Wkv_v[r*256 + c];
        }
        for (int i = tid; i < 8192; i += 256) {
            int n = i >> 7, k = i & 127;
            float w = (n < 32) ? Wq_u[k*32 + n] : Wkv_u[k*32 + (n - 32)];
            ws8[WUT8_OFF + n*128 + k] = f2fp8(w * 16.f);
        }
        __syncthreads();
        const float sc = 0.17677669529663687f * 256.f;  // 1/sqrt(32) * 256
        for (int i = tid; i < 4096; i += 256) {
            int h = i >> 10, r = (i >> 5) & 31, u = i & 31;
            float acc = 0.f;
            for (int c = 0; c < 32; ++c) acc += Aq[u*128 + h*32 + c] * Ak[r*128 + h*32 + c];
            ws8[MT8_OFF + h*1024 + r*32 + u] = f2fp8(acc * sc);
        }
        if (tid < 32) {
            float a = 0.f;
            for (int att = 0; att < 128; ++att) a += kv_b[128 + att] * Wo_u[att*32 + tid];
            ov[tid] = a;
        }
        __syncthreads();
        if (tid < 128) {
            float a = 0.f;
            for (int u = 0; u < 32; ++u) a += ov[u] * Wo_v[u*128 + tid];
            cvec[tid] = a;
        }
    }
}

// ---------------- main fused kernel: 1 block = 1 window, 4 waves ----------------
// R17 base + MFMA-sum softmax: P8 stores UNNORMALIZED e*64 (x64 folded into exp2
// arg as +6); KVT8 rows 32..47 hold constant fp8 4.0 so one extra MFMA B-tile
// yields acc_sum = 256*sum(e) in the SAME lanes/rows as the pu tiles ->
// normalization is lane-local (rs = 8*rcp) in the P5 epilogue.
#define SRA 136   // RA8/XB byte/short stride
#define SHQ 40    // HUQ8/KV8 byte stride
#define SHB 72    // HB8/KVT8 byte stride

#define SM_RA8   0        //  8704  h -> pu -> t1 (fp8 [64][SRA])
#define SM_HUQ8  8704     //  2560  hu_q x4 fp8 [64][SHQ]
#define SM_KV8   11264    //  2560  hu_kv x4 fp8 [64][SHQ] (A of scores)
#define SM_KVT8  13824    //  3456  v fp8 [48][SHB]: rows 0-31 v x4, rows 32-47 const 4.0
#define SM_HB8   17280    // 18432  per head [64][SHB]: qt8 then P8; later XB bf16 [64][136]
#define SM_TOTAL 35712

__global__ __launch_bounds__(256, 4) void fam_main(
    const float* __restrict__ x, const unsigned char* __restrict__ ws8,
    const float* __restrict__ gamma, const float* __restrict__ b1,
    const float* __restrict__ b2, const float* __restrict__ gmlp_p,
    float* __restrict__ out)
{
    __shared__ __align__(16) unsigned char SM[SM_TOTAL];
    unsigned char* RA8  = SM + SM_RA8;
    unsigned char* HUQ8 = SM + SM_HUQ8;
    unsigned char* KV8  = SM + SM_KV8;
    unsigned char* KVT8 = SM + SM_KVT8;

    const float* cvec = (const float*)(ws8 + CVEC_OFF);
    const int tid = threadIdx.x;
    const int l   = tid & 63;
    const int wv  = tid >> 6;
    const int l15 = l & 15;
    const int lg  = l >> 4;
    const size_t base = (size_t)blockIdx.x * 8192;
    const float* __restrict__ xw   = x + base;
    float* __restrict__       outw = out + base;
    const int n0 = wv * 32;

    // ---- P1: LN1 -> h (fp8 x1) in RA8 ; fill KVT8 ones-rows (fp8 4.0) ----
    if (tid < 72) {
        unsigned* p = (unsigned*)(KVT8 + 32*SHB + tid*16);
        p[0] = 0x48484848u; p[1] = 0x48484848u; p[2] = 0x48484848u; p[3] = 0x48484848u;
    }
    {
        int s = tid >> 2, c = tid & 3;
        float4 xr1[8];
        float sum = 0.f, sq = 0.f;
        #pragma unroll
        for (int j = 0; j < 8; ++j) {
            xr1[j] = *(const float4*)&xw[s*128 + c*32 + j*4];
            sum += xr1[j].x + xr1[j].y + xr1[j].z + xr1[j].w;
            sq  += xr1[j].x*xr1[j].x + xr1[j].y*xr1[j].y + xr1[j].z*xr1[j].z + xr1[j].w*xr1[j].w;
        }
        sum += __shfl_xor(sum, 1); sq += __shfl_xor(sq, 1);
        sum += __shfl_xor(sum, 2); sq += __shfl_xor(sq, 2);
        float mean = sum * (1.f/128.f);
        float var  = sq * (1.f/128.f) - mean*mean;
        float rinv = rsqrtf(var + 1e-5f);
        #pragma unroll
        for (int j = 0; j < 8; ++j) {
            unsigned w = 0;
            w = __builtin_amdgcn_cvt_pk_fp8_f32((xr1[j].x - mean)*rinv, (xr1[j].y - mean)*rinv, w, false);
            w = __builtin_amdgcn_cvt_pk_fp8_f32((xr1[j].z - mean)*rinv, (xr1[j].w - mean)*rinv, w, true);
            *(unsigned*)&RA8[s*SRA + c*32 + j*4] = w;
        }
    }
    __syncthreads();   // B1

    // ---- P2: [hu_q(32) | hu_kv(32)] = h @ Wu  (fp8 MFMA, acc = hu x16) ----
    {
        long bfr[4];
        #pragma unroll
        for (int kb = 0; kb < 4; ++kb)
            bfr[kb] = ld8(ws8 + WUT8_OFF + (wv*16 + l15)*128 + kb*32 + lg*8);
        #pragma unroll
        for (int m = 0; m < 4; ++m) {
            f32x4 acc = {0.f, 0.f, 0.f, 0.f};
            #pragma unroll
            for (int kb = 0; kb < 4; ++kb) {
                long a = ld8(RA8 + (m*16 + l15)*SRA + kb*32 + lg*8);
                acc = __builtin_amdgcn_mfma_f32_16x16x32_fp8_fp8(a, bfr[kb], acc, 0, 0, 0);
            }
            if (wv < 2) {
                int col = wv*16 + l15;
                #pragma unroll
                for (int j = 0; j < 4; ++j)
                    HUQ8[(m*16 + lg*4 + j)*SHQ + col] = f2fp8(acc[j] * 0.25f);  // hu x4
            } else {
                int u = (wv - 2)*16 + l15;
                #pragma unroll
                for (int j = 0; j < 4; ++j)
                    KV8[(m*16 + lg*4 + j)*SHQ + u] = f2fp8(acc[j] * 0.25f);     // kv x4
                unsigned w = 0;
                w = __builtin_amdgcn_cvt_pk_fp8_f32(acc[0]*0.25f, acc[1]*0.25f, w, false);
                w = __builtin_amdgcn_cvt_pk_fp8_f32(acc[2]*0.25f, acc[3]*0.25f, w, true);
                *(unsigned*)&KVT8[u*SHB + m*16 + lg*4] = w;                     // v x4
            }
        }
    }
    __syncthreads();   // B2

    // ---- P3/P4/P5: per-head attention, wave-local (h = wv), all fp8 ----
    {
        const int h = wv;
        unsigned char* HB8h = SM + SM_HB8 + h*4608;
        // P3: qt = hu_q @ M_h  (acc = qt x1024) -> qt8 = qt x64
        long bm0 = ld8(ws8 + MT8_OFF + h*1024 + l15*32 + lg*8);
        long bm1 = ld8(ws8 + MT8_OFF + h*1024 + (16 + l15)*32 + lg*8);
        #pragma unroll
        for (int m = 0; m < 4; ++m) {
            long aq = ld8(HUQ8 + (m*16 + l15)*SHQ + lg*8);
            f32x4 z = {0.f, 0.f, 0.f, 0.f};
            f32x4 a0 = __builtin_amdgcn_mfma_f32_16x16x32_fp8_fp8(aq, bm0, z, 0, 0, 0);
            f32x4 a1 = __builtin_amdgcn_mfma_f32_16x16x32_fp8_fp8(aq, bm1, z, 0, 0, 0);
            #pragma unroll
            for (int j = 0; j < 4; ++j) {
                int row = (m*16 + lg*4 + j)*SHB;
                HB8h[row + l15]      = f2fp8(a0[j] * 0.0625f);
                HB8h[row + 16 + l15] = f2fp8(a1[j] * 0.0625f);
            }
        }
        // P4: S^T[t][s] (swapped), acc = score x256
        long av[4], bq[4];
        #pragma unroll
        for (int m = 0; m < 4; ++m) av[m] = ld8(KV8 + (m*16 + l15)*SHQ + lg*8);
        #pragma unroll
        for (int n = 0; n < 4; ++n) bq[n] = ld8(HB8h + (n*16 + l15)*SHB + lg*8);
        f32x4 cc[4][4];
        #pragma unroll
        for (int m = 0; m < 4; ++m)
            #pragma unroll
            for (int n = 0; n < 4; ++n) {
                f32x4 z = {0.f, 0.f, 0.f, 0.f};
                cc[m][n] = __builtin_amdgcn_mfma_f32_16x16x32_fp8_fp8(av[m], bq[n], z, 0, 0, 0);
            }
        // softmax numerators only: P8 = 64*exp(score) = exp2(fma(cc, c1, 6));
        // no reduce here -- the row-sum comes from the ones-tile MFMA in P5.
        const float c1 = 0.0056355275f;  // 2^-8 * log2(e)
        #pragma unroll
        for (int n = 0; n < 4; ++n) {
            int srow = (n*16 + l15) * SHB;
            #pragma unroll
            for (int m = 0; m < 4; ++m) {
                float e0 = exp2f(fminf(fmaf(cc[m][n][0], c1, 6.f), 14.f));
                float e1 = exp2f(fminf(fmaf(cc[m][n][1], c1, 6.f), 14.f));
                float e2 = exp2f(fminf(fmaf(cc[m][n][2], c1, 6.f), 14.f));
                float e3 = exp2f(fminf(fmaf(cc[m][n][3], c1, 6.f), 14.f));
                unsigned w = 0;
                w = __builtin_amdgcn_cvt_pk_fp8_f32(e0, e1, w, false);
                w = __builtin_amdgcn_cvt_pk_fp8_f32(e2, e3, w, true);
                *(unsigned*)&HB8h[srow + m*16 + lg*4] = w;
            }
        }
        // P5: pu_raw = P8 @ V (acc = 256*sum(e*v)); sum tile (ones rows) gives
        // acc_sum = 256*sum(e) in identical lanes -> pu8 = pu x8 lane-locally.
        long a8[4][2], b8[2][2], bs[2];
        #pragma unroll
        for (int m = 0; m < 4; ++m)
            #pragma unroll
            for (int kb = 0; kb < 2; ++kb)
                a8[m][kb] = ld8(HB8h + (m*16 + l15)*SHB + kb*32 + lg*8);
        #pragma unroll
        for (int nn = 0; nn < 2; ++nn)
            #pragma unroll
            for (int kb = 0; kb < 2; ++kb)
                b8[nn][kb] = ld8(KVT8 + (nn*16 + l15)*SHB + kb*32 + lg*8);
        #pragma unroll
        for (int kb = 0; kb < 2; ++kb)
            bs[kb] = ld8(KVT8 + (32 + l15)*SHB + kb*32 + lg*8);
        #pragma unroll
        for (int m = 0; m < 4; ++m) {
            f32x4 accs = {0.f,0.f,0.f,0.f};
            accs = __builtin_amdgcn_mfma_f32_16x16x32_fp8_fp8(a8[m][0], bs[0], accs, 0, 0, 0);
            accs = __builtin_amdgcn_mfma_f32_16x16x32_fp8_fp8(a8[m][1], bs[1], accs, 0, 0, 0);
            f32x4 acc[2];
            #pragma unroll
            for (int nn = 0; nn < 2; ++nn) {
                acc[nn] = (f32x4){0.f,0.f,0.f,0.f};
                acc[nn] = __builtin_amdgcn_mfma_f32_16x16x32_fp8_fp8(a8[m][0], b8[nn][0], acc[nn], 0, 0, 0);
                acc[nn] = __builtin_amdgcn_mfma_f32_16x16x32_fp8_fp8(a8[m][1], b8[nn][1], acc[nn], 0, 0, 0);
            }
            #pragma unroll
            for (int j = 0; j < 4; ++j) {
                float rs8 = 8.f * __builtin_amdgcn_rcpf(accs[j]);
                int row = (m*16 + lg*4 + j)*SRA + h*32;
                RA8[row + l15]      = f2fp8(acc[0][j] * rs8);
                RA8[row + 16 + l15] = f2fp8(acc[1][j] * rs8);
            }
        }
    }
    __syncthreads();   // B3: pu8 in RA8 complete; HB8 dead -> XB

    float x1v[4][2][4];
    short* XB = (short*)(SM + SM_HB8);   // x1/h2 bf16 [64][136]

    // ---- P6: upd = pu8 @ O8 (acc = upd x1024); x1 = x + gm*(acc/1024 + cv) ----
    {
        float xr[4][2][4];
        #pragma unroll
        for (int m = 0; m < 4; ++m)
            #pragma unroll
            for (int nn = 0; nn < 2; ++nn)
                #pragma unroll
                for (int j = 0; j < 4; ++j)
                    xr[m][nn][j] = xw[(m*16 + lg*4 + j)*128 + n0 + nn*16 + l15];
        long bo[2][4];
        float cv[2], gm[2];
        #pragma unroll
        for (int nn = 0; nn < 2; ++nn) {
            int col = n0 + nn*16 + l15;
            #pragma unroll
            for (int kb = 0; kb < 4; ++kb)
                bo[nn][kb] = ld8(ws8 + OT8_OFF + col*128 + kb*32 + lg*8);
            cv[nn] = cvec[col];
            gm[nn] = gamma[col];
        }
        f32x4 acc[4][2];
        #pragma unroll
        for (int m = 0; m < 4; ++m)
            #pragma unroll
            for (int nn = 0; nn < 2; ++nn) acc[m][nn] = (f32x4){0.f,0.f,0.f,0.f};
        #pragma unroll
        for (int m = 0; m < 4; ++m) {
            long a[4];
            #pragma unroll
            for (int kb = 0; kb < 4; ++kb)
                a[kb] = ld8(RA8 + (m*16 + l15)*SRA + kb*32 + lg*8);
            #pragma unroll
            for (int kb = 0; kb < 4; ++kb)
                #pragma unroll
                for (int nn = 0; nn < 2; ++nn)
                    acc[m][nn] = __builtin_amdgcn_mfma_f32_16x16x32_fp8_fp8(a[kb], bo[nn][kb], acc[m][nn], 0, 0, 0);
        }
        // XB does not alias RA8: no interior barrier needed
        #pragma unroll
        for (int m = 0; m < 4; ++m)
            #pragma unroll
            for (int nn = 0; nn < 2; ++nn)
                #pragma unroll
                for (int j = 0; j < 4; ++j) {
                    int row = m*16 + lg*4 + j;
                    float v = xr[m][nn][j] + gm[nn] * (acc[m][nn][j] * 9.765625e-4f + cv[nn]);
                    x1v[m][nn][j] = v;
                    XB[row*SRA + n0 + nn*16 + l15] = f2bf(v);
                }
    }
    __syncthreads();   // B4: x1 bf16 in XB complete

    // ---- P7: LN2 on XB in place (bf16, proven) ----
    {
        int s = tid >> 2, c = tid & 3;
        float sum = 0.f, sq = 0.f;
        #pragma unroll
        for (int jj = 0; jj < 8; ++jj) {
            s16x4 hv = *(const s16x4*)&XB[s*SRA + c*32 + jj*4];
            #pragma unroll
            for (int e = 0; e < 4; ++e) {
                float f = bf2f(hv[e]);
                sum += f; sq += f*f;
            }
        }
        sum += __shfl_xor(sum, 1); sq += __shfl_xor(sq, 1);
        sum += __shfl_xor(sum, 2); sq += __shfl_xor(sq, 2);
        float mean = sum * (1.f/128.f);
        float var  = sq * (1.f/128.f) - mean*mean;
        float rinv = rsqrtf(var + 1e-5f);
        #pragma unroll
        for (int jj = 0; jj < 8; ++jj) {
            s16x4 hv = *(const s16x4*)&XB[s*SRA + c*32 + jj*4];
            s16x4 ov;
            #pragma unroll
            for (int e = 0; e < 4; ++e) ov[e] = f2bf((bf2f(hv[e]) - mean) * rinv);
            *(s16x4*)&XB[s*SRA + c*32 + jj*4] = ov;
        }
    }
    __syncthreads();   // B5: h2 in XB

    // ---- P8: t1 = gelu(h2 @ W1 + b1) (bf16 MFMA) -> t1 x8 fp8 into RA8 ----
    {
        bf16x8 bw1[2][4];
        float bb1[2];
        #pragma unroll
        for (int nn = 0; nn < 2; ++nn) {
            #pragma unroll
            for (int k = 0; k < 4; ++k)
                bw1[nn][k] = ldbf8(&((const short*)(ws8 + W1T_OFF))[(n0 + nn*16 + l15)*128 + k*32 + lg*8]);
            bb1[nn] = b1[n0 + nn*16 + l15];
        }
        #pragma unroll
        for (int m = 0; m < 4; ++m) {
            bf16x8 a[4];
            #pragma unroll
            for (int k = 0; k < 4; ++k)
                a[k] = ldbf8(&XB[(m*16 + l15)*SRA + k*32 + lg*8]);
            #pragma unroll
            for (int nn = 0; nn < 2; ++nn) {
                f32x4 acc = {0.f,0.f,0.f,0.f};
                #pragma unroll
                for (int k = 0; k < 4; ++k)
                    acc = __builtin_amdgcn_mfma_f32_16x16x32_bf16(a[k], bw1[nn][k], acc, 0, 0, 0);
                #pragma unroll
                for (int j = 0; j < 4; ++j) {
                    float t = acc[j] + bb1[nn];
                    // gelu(t) = t*sigmoid(1.5958(t+0.044715t^3)); exp2-folded constants
                    float u2 = t*t;
                    float p = fmaf(-0.1029417f, u2, -2.3021622f);
                    float g = t * __builtin_amdgcn_rcpf(1.f + exp2f(t*p));
                    RA8[(m*16 + lg*4 + j)*SRA + n0 + nn*16 + l15] = f2fp8(g * 8.f);
                }
            }
        }
    }
    __syncthreads();   // B6: t1 x8 in RA8

    // ---- P9: m = t1 @ W2 (acc = m x128); out = x1(reg) + gmlp*(acc/128 + b2) ----
    {
        const float gmv = gmlp_p[0];
        long bw[2][4];
        float bb[2];
        #pragma unroll
        for (int nn = 0; nn < 2; ++nn) {
            int col = n0 + nn*16 + l15;
            #pragma unroll
            for (int kb = 0; kb < 4; ++kb)
                bw[nn][kb] = ld8(ws8 + W2T8_OFF + col*128 + kb*32 + lg*8);
            bb[nn] = b2[col];
        }
        #pragma unroll
        for (int m = 0; m < 4; ++m) {
            long a[4];
            #pragma unroll
            for (int kb = 0; kb < 4; ++kb)
                a[kb] = ld8(RA8 + (m*16 + l15)*SRA + kb*32 + lg*8);
            #pragma unroll
            for (int nn = 0; nn < 2; ++nn) {
                f32x4 acc = {0.f,0.f,0.f,0.f};
                #pragma unroll
                for (int kb = 0; kb < 4; ++kb)
                    acc = __builtin_amdgcn_mfma_f32_16x16x32_fp8_fp8(a[kb], bw[nn][kb], acc, 0, 0, 0);
                #pragma unroll
                for (int j = 0; j < 4; ++j)
                    outw[(m*16 + lg*4 + j)*128 + n0 + nn*16 + l15] =
                        x1v[m][nn][j] + gmv * (acc[j] * 0.0078125f + bb[nn]);
            }
        }
    }
}

extern "C" void kernel_launch(void* const* d_in, const int* in_sizes, int n_in,
                              void* d_out, int out_size, void* d_ws, size_t ws_size,
                              hipStream_t stream) {
    const float* x     = (const float*)d_in[0];
    const float* Wq_u  = (const float*)d_in[1];
    const float* Wq_v  = (const float*)d_in[2];
    const float* Wkv_u = (const float*)d_in[3];
    const float* Wkv_v = (const float*)d_in[4];
    const float* kv_b  = (const float*)d_in[5];
    const float* Wo_u  = (const float*)d_in[6];
    const float* Wo_v  = (const float*)d_in[7];
    const float* gamma = (const float*)d_in[8];
    const float* W1    = (const float*)d_in[9];
    const float* b1    = (const float*)d_in[10];
    const float* W2    = (const float*)d_in[11];
    const float* b2    = (const float*)d_in[12];
    const float* gmlp  = (const float*)d_in[13];
    unsigned char* ws8 = (unsigned char*)d_ws;
    float* out = (float*)d_out;

    fam_pre<<<49, 256, 0, stream>>>(Wq_u, Wq_v, Wkv_u, Wkv_v, kv_b, Wo_u, Wo_v, W1, W2, ws8);
    fam_main<<<NWIN, 256, 0, stream>>>(x, ws8, gamma, b1, b2, gmlp, out);
}

// Round 20
// 89.594 us; speedup vs baseline: 1.0969x; 1.0420x over previous
//
#include <hip/hip_runtime.h>

// B=2,G=1024,S=64,L=16,F=8 -> LF=128, ATT=128, RANK=32, HC=32, NH=4. NWIN=2048.
#define NWIN 2048

// ws layout (BYTE offsets). Total 86528 B (under proven 123392 budget).
#define QKVT8_OFF 0      // uchar [160][128]: rows 0-127 QT_tab^T x256 (fused Wq_u*M, incl 1/sqrt32)
                         //                   rows 128-159 Wkv_u^T x16
#define OT8_OFF  20480   // uchar [128][128]  O^T x128
#define W1T_OFF  36864   // short [128][128]  W1^T bf16 (x1)
#define W2T8_OFF 69632   // uchar [128][128]  W2^T x16
#define CVEC_OFF 86016   // float [128]

typedef __attribute__((ext_vector_type(8))) __bf16 bf16x8;
typedef __attribute__((ext_vector_type(8))) short s16x8;
typedef __attribute__((ext_vector_type(4))) short s16x4;
typedef __attribute__((ext_vector_type(4))) float f32x4;

static __device__ inline short f2bf(float f) {
    __bf16 b = (__bf16)f;
    return __builtin_bit_cast(short, b);
}
static __device__ inline float bf2f(short h) {
    unsigned u = ((unsigned)(unsigned short)h) << 16;
    return __builtin_bit_cast(float, u);
}
static __device__ inline bf16x8 ldbf8(const short* p) {
    return __builtin_bit_cast(bf16x8, *(const s16x8*)p);
}
static __device__ inline unsigned char f2fp8(float v) {
    return (unsigned char)__builtin_amdgcn_cvt_pk_fp8_f32(v, v, 0u, false);
}
static __device__ inline long ld8(const void* p) {
    return *(const long*)p;
}

// ---------------- precompute: fp8 tables (scales exact powers of 2) ----------------
__global__ __launch_bounds__(256) void fam_pre(
    const float* __restrict__ Wq_u, const float* __restrict__ Wq_v,
    const float* __restrict__ Wkv_u, const float* __restrict__ Wkv_v,
    const float* __restrict__ kv_b, const float* __restrict__ Wo_u,
    const float* __restrict__ Wo_v, const float* __restrict__ W1,
    const float* __restrict__ W2, unsigned char* __restrict__ ws8)
{
    const int b = blockIdx.x, tid = threadIdx.x;
    float* cvec = (float*)(ws8 + CVEC_OFF);
    if (b < 16) {
        __shared__ float Wv[4096];   // Wkv_v v-part [r][c]
        __shared__ float Wu[4096];   // Wo_u [att][u]
        __shared__ float N[4096];    // N[h][u][r]
        for (int i = tid; i < 4096; i += 256) {
            int r = i >> 7, c = i & 127;
            Wv[i] = Wkv_v[r*256 + 128 + c];
            Wu[i] = Wo_u[i];
        }
        __syncthreads();
        for (int i = tid; i < 4096; i += 256) {
            int h = i >> 10, u = (i >> 5) & 31, r = i & 31;
            float acc = 0.f;
            for (int c = 0; c < 32; ++c) acc += Wv[r*128 + h*32 + c] * Wu[(h*32 + c)*32 + u];
            N[i] = acc;
        }
        __syncthreads();
        for (int i = tid; i < 1024; i += 256) {
            int jj = i >> 7, hr = i & 127;
            int j = b*8 + jj, h = hr >> 5, r = hr & 31;
            float acc = 0.f;
            for (int u = 0; u < 32; ++u) acc += N[h*1024 + u*32 + r] * Wo_v[u*128 + j];
            ws8[OT8_OFF + j*128 + hr] = f2fp8(acc * 128.f);
        }
    } else if (b < 32) {
        short* w1t = (short*)(ws8 + W1T_OFF);
        int i0 = (b - 16) * 8;
        for (int t = tid; t < 1024; t += 256) {
            int ii = t >> 7, k = t & 127, i = i0 + ii;
            w1t[i*128 + k] = f2bf(W1[k*128 + i]);
        }
    } else if (b < 48) {
        int j0 = (b - 32) * 8;
        for (int t = tid; t < 1024; t += 256) {
            int jj = t >> 7, k = t & 127, j = j0 + jj;
            ws8[W2T8_OFF + j*128 + k] = f2fp8(W2[k*128 + j] * 16.f);
        }
    } else {
        // QKVT slices: sl = 0..7; each builds M redundantly, writes 16 QT rows + 4 KV rows
        const int sl = b - 48;
        __shared__ float Msh[4096];   // M[h][u][r] (incl 1/sqrt32)
        __shared__ float ov[32];
        const float sc = 0.17677669529663687f;  // 1/sqrt(32)
        for (int i = tid; i < 4096; i += 256) {
            int h = i >> 10, u = (i >> 5) & 31, r = i & 31;
            float acc = 0.f;
            for (int c = 0; c < 32; ++c)
                acc += Wq_v[u*128 + h*32 + c] * Wkv_v[r*256 + h*32 + c];
            Msh[i] = acc * sc;
        }
        __syncthreads();
        // QT_tab rows c (= output col): tab[c][k] = sum_u Wq_u[k][u]*M[h(c)][u][r(c)], x256
        for (int i = tid; i < 2048; i += 256) {
            int c = sl*16 + (i >> 7), k = i & 127;
            int h = c >> 5, r = c & 31;
            float acc = 0.f;
            for (int u = 0; u < 32; ++u) acc += Wq_u[k*32 + u] * Msh[h*1024 + u*32 + r];
            ws8[QKVT8_OFF + c*128 + k] = f2fp8(acc * 256.f);
        }
        // KV rows (x16)
        for (int i = tid; i < 512; i += 256) {
            int u = sl*4 + (i >> 7), k = i & 127;
            ws8[QKVT8_OFF + (128 + u)*128 + k] = f2fp8(Wkv_u[k*32 + u] * 16.f);
        }
        if (sl == 0) {
            if (tid < 32) {
                float a = 0.f;
                for (int att = 0; att < 128; ++att) a += kv_b[128 + att] * Wo_u[att*32 + tid];
                ov[tid] = a;
            }
            __syncthreads();
            if (tid < 128) {
                float a = 0.f;
                for (int u = 0; u < 32; ++u) a += ov[u] * Wo_v[u*128 + tid];
                cvec[tid] = a;
            }
        }
    }
}

// ---------------- main fused kernel: 1 block = 1 window, 4 waves ----------------
// R14 champion (bench 89.49us, passed): fused-QT fp8 pipeline, (256,4), no spill.
#define SRA 136   // RA8/XB byte/short stride
#define SHQ 40    // KV8 byte stride
#define SHB 72    // HB8/KVT8 byte stride

#define SM_RA8   0        //  8704  h -> pu -> t1 (fp8 [64][SRA])
#define SM_KV8   8704     //  2560  hu_kv x4 fp8 [64][SHQ] (A of scores)
#define SM_KVT8  11264    //  2304  hu_kv^T x4 fp8 [32][SHB] (B of PV)
#define SM_HB8   13568    // 18432  per head [64][SHB]: qt8 then P8; later XB bf16 [64][136]
#define SM_TOTAL 32000

__global__ __launch_bounds__(256, 4) void fam_main(
    const float* __restrict__ x, const unsigned char* __restrict__ ws8,
    const float* __restrict__ gamma, const float* __restrict__ b1,
    const float* __restrict__ b2, const float* __restrict__ gmlp_p,
    float* __restrict__ out)
{
    __shared__ __align__(16) unsigned char SM[SM_TOTAL];
    unsigned char* RA8  = SM + SM_RA8;
    unsigned char* KV8  = SM + SM_KV8;
    unsigned char* KVT8 = SM + SM_KVT8;

    const float* cvec = (const float*)(ws8 + CVEC_OFF);
    const int tid = threadIdx.x;
    const int l   = tid & 63;
    const int wv  = tid >> 6;
    const int l15 = l & 15;
    const int lg  = l >> 4;
    const size_t base = (size_t)blockIdx.x * 8192;
    const float* __restrict__ xw   = x + base;
    float* __restrict__       outw = out + base;
    const int n0 = wv * 32;

    // ---- P1: LN1 -> h (fp8 x1) in RA8 ----
    {
        int s = tid >> 2, c = tid & 3;
        float4 xr1[8];
        float sum = 0.f, sq = 0.f;
        #pragma unroll
        for (int j = 0; j < 8; ++j) {
            xr1[j] = *(const float4*)&xw[s*128 + c*32 + j*4];
            sum += xr1[j].x + xr1[j].y + xr1[j].z + xr1[j].w;
            sq  += xr1[j].x*xr1[j].x + xr1[j].y*xr1[j].y + xr1[j].z*xr1[j].z + xr1[j].w*xr1[j].w;
        }
        sum += __shfl_xor(sum, 1); sq += __shfl_xor(sq, 1);
        sum += __shfl_xor(sum, 2); sq += __shfl_xor(sq, 2);
        float mean = sum * (1.f/128.f);
        float var  = sq * (1.f/128.f) - mean*mean;
        float rinv = rsqrtf(var + 1e-5f);
        #pragma unroll
        for (int j = 0; j < 8; ++j) {
            unsigned w = 0;
            w = __builtin_amdgcn_cvt_pk_fp8_f32((xr1[j].x - mean)*rinv, (xr1[j].y - mean)*rinv, w, false);
            w = __builtin_amdgcn_cvt_pk_fp8_f32((xr1[j].z - mean)*rinv, (xr1[j].w - mean)*rinv, w, true);
            *(unsigned*)&RA8[s*SRA + c*32 + j*4] = w;
        }
    }
    __syncthreads();   // B1

    // ---- P2 (fused): [QT(128) | KV(32)] = h @ QKVT8 ----
    // wave wv: strips wv (qt head wv>>1), wv+4 (qt head 2+(wv>>1)), and 6+wv (kv, wv>=2)
    {
        long bA[4], bB[4], bC[4];
        #pragma unroll
        for (int kb = 0; kb < 4; ++kb) {
            bA[kb] = ld8(ws8 + QKVT8_OFF + (wv*16 + l15)*128 + kb*32 + lg*8);
            bB[kb] = ld8(ws8 + QKVT8_OFF + ((wv + 4)*16 + l15)*128 + kb*32 + lg*8);
        }
        if (wv >= 2) {
            #pragma unroll
            for (int kb = 0; kb < 4; ++kb)
                bC[kb] = ld8(ws8 + QKVT8_OFF + ((6 + wv)*16 + l15)*128 + kb*32 + lg*8);
        }
        unsigned char* HBA = SM + SM_HB8 + (wv >> 1)*4608;        // head wv>>1
        unsigned char* HBB = SM + SM_HB8 + (2 + (wv >> 1))*4608;  // head 2+(wv>>1)
        const int rr = (wv & 1)*16 + l15;                          // col within head
        #pragma unroll
        for (int m = 0; m < 4; ++m) {
            long a[4];
            #pragma unroll
            for (int kb = 0; kb < 4; ++kb)
                a[kb] = ld8(RA8 + (m*16 + l15)*SRA + kb*32 + lg*8);
            f32x4 accA = {0.f,0.f,0.f,0.f}, accB = {0.f,0.f,0.f,0.f};
            #pragma unroll
            for (int kb = 0; kb < 4; ++kb) {
                accA = __builtin_amdgcn_mfma_f32_16x16x32_fp8_fp8(a[kb], bA[kb], accA, 0, 0, 0);
                accB = __builtin_amdgcn_mfma_f32_16x16x32_fp8_fp8(a[kb], bB[kb], accB, 0, 0, 0);
            }
            #pragma unroll
            for (int j = 0; j < 4; ++j) {
                int row = (m*16 + lg*4 + j)*SHB;
                HBA[row + rr] = f2fp8(accA[j] * 0.25f);   // qt8 = qt x64
                HBB[row + rr] = f2fp8(accB[j] * 0.25f);
            }
            if (wv >= 2) {
                f32x4 accC = {0.f,0.f,0.f,0.f};
                #pragma unroll
                for (int kb = 0; kb < 4; ++kb)
                    accC = __builtin_amdgcn_mfma_f32_16x16x32_fp8_fp8(a[kb], bC[kb], accC, 0, 0, 0);
                int u = (wv - 2)*16 + l15;
                #pragma unroll
                for (int j = 0; j < 4; ++j)
                    KV8[(m*16 + lg*4 + j)*SHQ + u] = f2fp8(accC[j] * 0.25f);   // kv x4
                unsigned w = 0;
                w = __builtin_amdgcn_cvt_pk_fp8_f32(accC[0]*0.25f, accC[1]*0.25f, w, false);
                w = __builtin_amdgcn_cvt_pk_fp8_f32(accC[2]*0.25f, accC[3]*0.25f, w, true);
                *(unsigned*)&KVT8[u*SHB + m*16 + lg*4] = w;                    // v x4
            }
        }
    }
    __syncthreads();   // B2: qt8 (all heads), kv, v complete

    // ---- P4/P5: per-head attention (h = wv); qt8 already in HB8h ----
    {
        const int h = wv;
        unsigned char* HB8h = SM + SM_HB8 + h*4608;
        // scores: S^T[t][s] (swapped operands), acc = score x256
        long av[4], bq[4];
        #pragma unroll
        for (int m = 0; m < 4; ++m) av[m] = ld8(KV8 + (m*16 + l15)*SHQ + lg*8);
        #pragma unroll
        for (int n = 0; n < 4; ++n) bq[n] = ld8(HB8h + (n*16 + l15)*SHB + lg*8);
        f32x4 cc[4][4];
        #pragma unroll
        for (int m = 0; m < 4; ++m)
            #pragma unroll
            for (int n = 0; n < 4; ++n) {
                f32x4 z = {0.f, 0.f, 0.f, 0.f};
                cc[m][n] = __builtin_amdgcn_mfma_f32_16x16x32_fp8_fp8(av[m], bq[n], z, 0, 0, 0);
            }
        // softmax over t (no max-reduce; scores tiny), P8 = P x64 (overwrites qt8 after reads)
        #pragma unroll
        for (int n = 0; n < 4; ++n) {
            float e[4][4];
            float sm = 0.f;
            #pragma unroll
            for (int m = 0; m < 4; ++m)
                #pragma unroll
                for (int j = 0; j < 4; ++j) {
                    e[m][j] = __expf(fminf(cc[m][n][j] * 0.00390625f, 30.f));
                    sm += e[m][j];
                }
            sm += __shfl_xor(sm, 16);
            sm += __shfl_xor(sm, 32);
            float rs64 = __builtin_amdgcn_rcpf(sm) * 64.f;
            int srow = (n*16 + l15) * SHB;
            #pragma unroll
            for (int m = 0; m < 4; ++m) {
                unsigned w = 0;
                w = __builtin_amdgcn_cvt_pk_fp8_f32(e[m][0]*rs64, e[m][1]*rs64, w, false);
                w = __builtin_amdgcn_cvt_pk_fp8_f32(e[m][2]*rs64, e[m][3]*rs64, w, true);
                *(unsigned*)&HB8h[srow + m*16 + lg*4] = w;
            }
        }
        // PV: pu = P @ V, acc = pu x256 -> pu8 = pu x8 into RA8
        long a8[4][2], b8[2][2];
        #pragma unroll
        for (int m = 0; m < 4; ++m)
            #pragma unroll
            for (int kb = 0; kb < 2; ++kb)
                a8[m][kb] = ld8(HB8h + (m*16 + l15)*SHB + kb*32 + lg*8);
        #pragma unroll
        for (int nn = 0; nn < 2; ++nn)
            #pragma unroll
            for (int kb = 0; kb < 2; ++kb)
                b8[nn][kb] = ld8(KVT8 + (nn*16 + l15)*SHB + kb*32 + lg*8);
        #pragma unroll
        for (int m = 0; m < 4; ++m)
            #pragma unroll
            for (int nn = 0; nn < 2; ++nn) {
                f32x4 acc = {0.f,0.f,0.f,0.f};
                acc = __builtin_amdgcn_mfma_f32_16x16x32_fp8_fp8(a8[m][0], b8[nn][0], acc, 0, 0, 0);
                acc = __builtin_amdgcn_mfma_f32_16x16x32_fp8_fp8(a8[m][1], b8[nn][1], acc, 0, 0, 0);
                #pragma unroll
                for (int j = 0; j < 4; ++j)
                    RA8[(m*16 + lg*4 + j)*SRA + h*32 + nn*16 + l15] = f2fp8(acc[j] * 0.03125f);
            }
    }
    __syncthreads();   // B3: pu8 in RA8 complete; HB8 dead -> XB

    float x1v[4][2][4];
    short* XB = (short*)(SM + SM_HB8);   // x1/h2 bf16 [64][136]

    // ---- P6: upd = pu8 @ O8 (acc = upd x1024); x1 = x + gm*(acc/1024 + cv) ----
    {
        float xr[4][2][4];
        #pragma unroll
        for (int m = 0; m < 4; ++m)
            #pragma unroll
            for (int nn = 0; nn < 2; ++nn)
                #pragma unroll
                for (int j = 0; j < 4; ++j)
                    xr[m][nn][j] = xw[(m*16 + lg*4 + j)*128 + n0 + nn*16 + l15];
        long bo[2][4];
        float cv[2], gm[2];
        #pragma unroll
        for (int nn = 0; nn < 2; ++nn) {
            int col = n0 + nn*16 + l15;
            #pragma unroll
            for (int kb = 0; kb < 4; ++kb)
                bo[nn][kb] = ld8(ws8 + OT8_OFF + col*128 + kb*32 + lg*8);
            cv[nn] = cvec[col];
            gm[nn] = gamma[col];
        }
        f32x4 acc[4][2];
        #pragma unroll
        for (int m = 0; m < 4; ++m)
            #pragma unroll
            for (int nn = 0; nn < 2; ++nn) acc[m][nn] = (f32x4){0.f,0.f,0.f,0.f};
        #pragma unroll
        for (int m = 0; m < 4; ++m) {
            long a[4];
            #pragma unroll
            for (int kb = 0; kb < 4; ++kb)
                a[kb] = ld8(RA8 + (m*16 + l15)*SRA + kb*32 + lg*8);
            #pragma unroll
            for (int kb = 0; kb < 4; ++kb)
                #pragma unroll
                for (int nn = 0; nn < 2; ++nn)
                    acc[m][nn] = __builtin_amdgcn_mfma_f32_16x16x32_fp8_fp8(a[kb], bo[nn][kb], acc[m][nn], 0, 0, 0);
        }
        // XB does not alias RA8: no interior barrier needed
        #pragma unroll
        for (int m = 0; m < 4; ++m)
            #pragma unroll
            for (int nn = 0; nn < 2; ++nn)
                #pragma unroll
                for (int j = 0; j < 4; ++j) {
                    int row = m*16 + lg*4 + j;
                    float v = xr[m][nn][j] + gm[nn] * (acc[m][nn][j] * 9.765625e-4f + cv[nn]);
                    x1v[m][nn][j] = v;
                    XB[row*SRA + n0 + nn*16 + l15] = f2bf(v);
                }
    }
    __syncthreads();   // B4: x1 bf16 in XB complete

    // ---- P7: LN2 on XB in place (bf16, proven) ----
    {
        int s = tid >> 2, c = tid & 3;
        float sum = 0.f, sq = 0.f;
        #pragma unroll
        for (int jj = 0; jj < 8; ++jj) {
            s16x4 hv = *(const s16x4*)&XB[s*SRA + c*32 + jj*4];
            #pragma unroll
            for (int e = 0; e < 4; ++e) {
                float f = bf2f(hv[e]);
                sum += f; sq += f*f;
            }
        }
        sum += __shfl_xor(sum, 1); sq += __shfl_xor(sq, 1);
        sum += __shfl_xor(sum, 2); sq += __shfl_xor(sq, 2);
        float mean = sum * (1.f/128.f);
        float var  = sq * (1.f/128.f) - mean*mean;
        float rinv = rsqrtf(var + 1e-5f);
        #pragma unroll
        for (int jj = 0; jj < 8; ++jj) {
            s16x4 hv = *(const s16x4*)&XB[s*SRA + c*32 + jj*4];
            s16x4 ov;
            #pragma unroll
            for (int e = 0; e < 4; ++e) ov[e] = f2bf((bf2f(hv[e]) - mean) * rinv);
            *(s16x4*)&XB[s*SRA + c*32 + jj*4] = ov;
        }
    }
    __syncthreads();   // B5: h2 in XB

    // ---- P8: t1 = gelu(h2 @ W1 + b1) (bf16 MFMA) -> t1 x8 fp8 into RA8 ----
    {
        const short* W1t = (const short*)(ws8 + W1T_OFF);
        bf16x8 bw1[2][4];
        float bb1[2];
        #pragma unroll
        for (int nn = 0; nn < 2; ++nn) {
            #pragma unroll
            for (int k = 0; k < 4; ++k)
                bw1[nn][k] = ldbf8(&W1t[(n0 + nn*16 + l15)*128 + k*32 + lg*8]);
            bb1[nn] = b1[n0 + nn*16 + l15];
        }
        #pragma unroll
        for (int m = 0; m < 4; ++m) {
            bf16x8 a[4];
            #pragma unroll
            for (int k = 0; k < 4; ++k)
                a[k] = ldbf8(&XB[(m*16 + l15)*SRA + k*32 + lg*8]);
            #pragma unroll
            for (int nn = 0; nn < 2; ++nn) {
                f32x4 acc = {0.f,0.f,0.f,0.f};
                #pragma unroll
                for (int k = 0; k < 4; ++k)
                    acc = __builtin_amdgcn_mfma_f32_16x16x32_bf16(a[k], bw1[nn][k], acc, 0, 0, 0);
                #pragma unroll
                for (int j = 0; j < 4; ++j) {
                    float t = acc[j] + bb1[nn];
                    float w = -1.5957691216057308f * (t + 0.044715f*t*t*t);
                    float g = t * __builtin_amdgcn_rcpf(1.f + __expf(w));
                    RA8[(m*16 + lg*4 + j)*SRA + n0 + nn*16 + l15] = f2fp8(g * 8.f);
                }
            }
        }
    }
    __syncthreads();   // B6: t1 x8 in RA8

    // ---- P9: m = t1 @ W2 (acc = m x128); out = x1(reg) + gmlp*(acc/128 + b2) ----
    {
        const float gmv = gmlp_p[0];
        long bw[2][4];
        float bb[2];
        #pragma unroll
        for (int nn = 0; nn < 2; ++nn) {
            int col = n0 + nn*16 + l15;
            #pragma unroll
            for (int kb = 0; kb < 4; ++kb)
                bw[nn][kb] = ld8(ws8 + W2T8_OFF + col*128 + kb*32 + lg*8);
            bb[nn] = b2[col];
        }
        #pragma unroll
        for (int m = 0; m < 4; ++m) {
            long a[4];
            #pragma unroll
            for (int kb = 0; kb < 4; ++kb)
                a[kb] = ld8(RA8 + (m*16 + l15)*SRA + kb*32 + lg*8);
            #pragma unroll
            for (int nn = 0; nn < 2; ++nn) {
                f32x4 acc = {0.f,0.f,0.f,0.f};
                #pragma unroll
                for (int kb = 0; kb < 4; ++kb)
                    acc = __builtin_amdgcn_mfma_f32_16x16x32_fp8_fp8(a[kb], bw[nn][kb], acc, 0, 0, 0);
                #pragma unroll
                for (int j = 0; j < 4; ++j)
                    outw[(m*16 + lg*4 + j)*128 + n0 + nn*16 + l15] =
                        x1v[m][nn][j] + gmv * (acc[j] * 0.0078125f + bb[nn]);
            }
        }
    }
}

extern "C" void kernel_launch(void* const* d_in, const int* in_sizes, int n_in,
                              void* d_out, int out_size, void* d_ws, size_t ws_size,
                              hipStream_t stream) {
    const float* x     = (const float*)d_in[0];
    const float* Wq_u  = (const float*)d_in[1];
    const float* Wq_v  = (const float*)d_in[2];
    const float* Wkv_u = (const float*)d_in[3];
    const float* Wkv_v = (const float*)d_in[4];
    const float* kv_b  = (const float*)d_in[5];
    const float* Wo_u  = (const float*)d_in[6];
    const float* Wo_v  = (const float*)d_in[7];
    const float* gamma = (const float*)d_in[8];
    const float* W1    = (const float*)d_in[9];
    const float* b1    = (const float*)d_in[10];
    const float* W2    = (const float*)d_in[11];
    const float* b2    = (const float*)d_in[12];
    const float* gmlp  = (const float*)d_in[13];
    unsigned char* ws8 = (unsigned char*)d_ws;
    float* out = (float*)d_out;

    fam_pre<<<56, 256, 0, stream>>>(Wq_u, Wq_v, Wkv_u, Wkv_v, kv_b, Wo_u, Wo_v, W1, W2, ws8);
    fam_main<<<NWIN, 256, 0, stream>>>(x, ws8, gamma, b1, b2, gmlp, out);
}